// Round 8
// baseline (312.532 us; speedup 1.0000x reference)
//
#include <hip/hip_runtime.h>

#define D_MODEL 768
#define NHEADS  12
#define SEQ     2048
#define BATCH   4
#define FF_DIM  3072
#define NTOK    (BATCH * SEQ)

typedef short short8 __attribute__((ext_vector_type(8)));
typedef float f32x4 __attribute__((ext_vector_type(4)));
typedef float f32x16 __attribute__((ext_vector_type(16)));
typedef int int4v __attribute__((ext_vector_type(4)));
typedef int int2v __attribute__((ext_vector_type(2)));
typedef unsigned short ushort4v __attribute__((ext_vector_type(4)));
typedef float float4v __attribute__((ext_vector_type(4)));

__device__ __forceinline__ short f2bf(float x) {
  unsigned u = __builtin_bit_cast(unsigned, x);
  u += 0x7fffu + ((u >> 16) & 1u);   // RNE
  return (short)(u >> 16);
}
__device__ __forceinline__ float bf2f(short x) {
  return __builtin_bit_cast(float, ((unsigned)(unsigned short)x) << 16);
}
__device__ __forceinline__ int cvtpk(float a, float b) {
  int r;
  asm("v_cvt_pk_bf16_f32 %0, %1, %2" : "=v"(r) : "v"(a), "v"(b));
  return r;  // lo16 = bf16(a), hi16 = bf16(b)
}
__device__ __forceinline__ float fexp2(float x) {
#if __has_builtin(__builtin_amdgcn_exp2f)
  return __builtin_amdgcn_exp2f(x);   // single v_exp_f32
#else
  return exp2f(x);
#endif
}
__device__ __forceinline__ float frcp(float x) {
#if __has_builtin(__builtin_amdgcn_rcpf)
  return __builtin_amdgcn_rcpf(x);    // single v_rcp_f32
#else
  return 1.f / x;
#endif
}
__device__ __forceinline__ void gll16(const void* g, void* l) {
  __builtin_amdgcn_global_load_lds(
      (const __attribute__((address_space(1))) void*)g,
      (__attribute__((address_space(3))) void*)l, 16, 0, 0);
}

// ---------------- prep: all weight transposes + bias concat + emb cast ----------------
__device__ __forceinline__ void wt_tile(float (*T)[65], const float* __restrict__ W,
                                        short* __restrict__ Wt, int K, int N,
                                        int bx, int by, int t) {
  const int c = t & 63, rb = t >> 6;
  const int k0 = by * 64, n0 = bx * 64;
#pragma unroll
  for (int i = 0; i < 16; ++i) {
    const int r = rb * 16 + i;
    T[c][r] = W[(size_t)(k0 + r) * N + n0 + c];
  }
  __syncthreads();
#pragma unroll
  for (int j = 0; j < 16; ++j) {
    const int idx = t + j * 256;
    const int nl = idx >> 6, kl = idx & 63;
    Wt[(size_t)(n0 + nl) * K + k0 + kl] = f2bf(T[nl][kl]);
  }
}

__global__ __launch_bounds__(256) void prep(
    const float* __restrict__ Wq, const float* __restrict__ Wk, const float* __restrict__ Wv,
    const float* __restrict__ Wo, const float* __restrict__ W1, const float* __restrict__ W2,
    const float* __restrict__ bq, const float* __restrict__ bk, const float* __restrict__ bv,
    const float* __restrict__ emb,
    short* __restrict__ wqkvt, short* __restrict__ wot, short* __restrict__ w1t,
    short* __restrict__ w2t, float* __restrict__ bqkv, short* __restrict__ x0) {
  __shared__ float T[64][65];
  const int bi = blockIdx.x;
  const int t = threadIdx.x;
  if (bi < 432) {
    const int s = bi / 144, l = bi % 144;
    const float* W = (s == 0) ? Wq : (s == 1) ? Wk : Wv;
    wt_tile(T, W, wqkvt + (size_t)s * 768 * 768, 768, 768, l % 12, l / 12, t);
  } else if (bi < 576) {
    const int l = bi - 432;
    wt_tile(T, Wo, wot, 768, 768, l % 12, l / 12, t);
  } else if (bi < 1152) {
    const int l = bi - 576;
    wt_tile(T, W1, w1t, 768, 3072, l % 48, l / 48, t);
  } else if (bi < 1728) {
    const int l = bi - 1152;
    wt_tile(T, W2, w2t, 3072, 768, l % 12, l / 12, t);
  } else if (bi == 1728) {
#pragma unroll
    for (int j = 0; j < 9; ++j) {
      const int i = t + j * 256;
      bqkv[i] = (i < 768) ? bq[i] : (i < 1536) ? bk[i - 768] : bv[i - 1536];
    }
  } else {
    const int i = (bi - 1729) * 256 + t;
    float4v v = *(const float4v*)(emb + (size_t)i * 4);
    ushort4v p;
    p[0] = (unsigned short)f2bf(v[0]);
    p[1] = (unsigned short)f2bf(v[1]);
    p[2] = (unsigned short)f2bf(v[2]);
    p[3] = (unsigned short)f2bf(v[3]);
    *(ushort4v*)(x0 + (size_t)i * 4) = p;
  }
}

// ---------------- GEMM: C[M,N] = A[M,K](bf16) x Bt[N,K](bf16)^T, fused epilogues ----
// EPI_QKV stores K and V in MFMA-FRAGMENT-MAJOR layouts so attention can read
// coalesced 1KB fragment blocks straight from global (no LDS, no barriers):
//   Kf[bh][kv>>5][slot=dk>>4][lane][8]  lane = (kv&31) + ((dk>>3)&1)*32, e = dk&7
//   Vf[bh][kv>>4][dblk=dk>>5][lane][8]  lane = (dk&31) + ((kv>>3)&1)*32, e = kv&7
enum { EPI_QKV = 0, EPI_WO = 1, EPI_RELU = 2, EPI_FF = 3 };

template <int EPI>
__global__ __launch_bounds__(256) void gemm_bt(const short* __restrict__ A,
                                               const short* __restrict__ Bt,
                                               const float* __restrict__ bias,
                                               const float* __restrict__ extraF,
                                               const short* __restrict__ extraB,
                                               void* __restrict__ outp,
                                               int M, int N, int K) {
  __shared__ short As[128 * 64];
  __shared__ short Bs[128 * 64];
  const int tid = threadIdx.x;
  const int lane = tid & 63, wid = tid >> 6;
  const int wr = wid >> 1, wc = wid & 1;
  const int l16 = lane & 15, lg = lane >> 4;
  const int brow = blockIdx.y * 128, bcol = blockIdx.x * 128;

  f32x4 acc[4][4];
#pragma unroll
  for (int i = 0; i < 4; ++i)
#pragma unroll
    for (int j = 0; j < 4; ++j) acc[i][j] = (f32x4){0.f, 0.f, 0.f, 0.f};

  for (int kt = 0; kt < K; kt += 64) {
    __syncthreads();
#pragma unroll
    for (int i = 0; i < 4; ++i) {
      const int c = wid * 256 + i * 64 + lane;
      const int row = c >> 3;
      const int gc = (c & 7) ^ (row & 7);           // pre-swizzled global source
      gll16(A + (size_t)(brow + row) * K + kt + gc * 8,
            (char*)As + (wid * 256 + i * 64) * 16);
      gll16(Bt + (size_t)(bcol + row) * K + kt + gc * 8,
            (char*)Bs + (wid * 256 + i * 64) * 16);
    }
    __syncthreads();
#pragma unroll
    for (int kc = 0; kc < 2; ++kc) {
      short8 af[4], bfr[4];
#pragma unroll
      for (int m = 0; m < 4; ++m) {
        const int row = wr * 64 + m * 16 + l16;
        const int ch = (kc * 4 + lg) ^ (row & 7);
        af[m] = *(const short8*)((const char*)As + row * 128 + ch * 16);
      }
#pragma unroll
      for (int n = 0; n < 4; ++n) {
        const int row = wc * 64 + n * 16 + l16;
        const int ch = (kc * 4 + lg) ^ (row & 7);
        bfr[n] = *(const short8*)((const char*)Bs + row * 128 + ch * 16);
      }
#pragma unroll
      for (int m = 0; m < 4; ++m)
#pragma unroll
        for (int n = 0; n < 4; ++n)
          acc[m][n] = __builtin_amdgcn_mfma_f32_16x16x32_bf16(af[m], bfr[n],
                                                              acc[m][n], 0, 0, 0);
    }
  }

  const int mbase = brow + wr * 64;
  const int nbase = bcol + wc * 64;

  if constexpr (EPI == EPI_QKV) {
    short* qb_ = (short*)outp;
    short* kf_ = qb_ + (size_t)NTOK * D_MODEL;
    short* vf_ = kf_ + (size_t)NTOK * D_MODEL;
    const int type = nbase / 768;  // block-uniform
#pragma unroll
    for (int ni = 0; ni < 4; ++ni) {
      const int n = nbase + ni * 16 + l16;
      const float bv = bias[n];
      const int ncol = n - type * 768;
      const int h = ncol >> 6, dk = ncol & 63;
      if (type == 0) {  // Q: row-major [bh][s][64], pre-scaled
#pragma unroll
        for (int mi = 0; mi < 4; ++mi) {
#pragma unroll
          for (int r = 0; r < 4; ++r) {
            const int m = mbase + mi * 16 + lg * 4 + r;
            const int bidx = m >> 11, sidx = m & 2047;
            qb_[(((size_t)bidx * NHEADS + h) * SEQ + sidx) * 64 + dk] =
                f2bf((acc[mi][ni][r] + bv) * (0.125f * 1.44269504f));
          }
        }
      } else if (type == 1) {  // K: fragment-major
        const int slot = dk >> 4, dhi = (dk >> 3) & 1, e = dk & 7;
#pragma unroll
        for (int mi = 0; mi < 4; ++mi) {
#pragma unroll
          for (int r = 0; r < 4; ++r) {
            const int m = mbase + mi * 16 + lg * 4 + r;
            const int bidx = m >> 11, sidx = m & 2047;
            const size_t bh = (size_t)bidx * NHEADS + h;
            const size_t idx =
                (((bh * 64 + (sidx >> 5)) * 4 + slot) * 64 + ((sidx & 31) + dhi * 32)) * 8 + e;
            kf_[idx] = f2bf(acc[mi][ni][r] + bv);
          }
        }
      } else {  // V: fragment-major, 4 consecutive kv per lane -> 8B packed store
        const int dblk = dk >> 5, lanef = dk & 31;
#pragma unroll
        for (int mi = 0; mi < 4; ++mi) {
          const int m0 = mbase + mi * 16 + lg * 4;
          const int bidx = m0 >> 11, s0 = m0 & 2047;
          const size_t bh = (size_t)bidx * NHEADS + h;
          ushort4v pk;
#pragma unroll
          for (int r = 0; r < 4; ++r) pk[r] = (unsigned short)f2bf(acc[mi][ni][r] + bv);
          const size_t idx =
              (((bh * 128 + (s0 >> 4)) * 2 + dblk) * 64 + (lanef + ((s0 >> 3) & 1) * 32)) * 8 +
              (s0 & 7);
          *(ushort4v*)(vf_ + idx) = pk;
        }
      }
    }
  } else if constexpr (EPI == EPI_WO) {
    short* o = (short*)outp;
#pragma unroll
    for (int ni = 0; ni < 4; ++ni) {
      const int n = nbase + ni * 16 + l16;
      const float bv = bias[n];
#pragma unroll
      for (int mi = 0; mi < 4; ++mi)
#pragma unroll
        for (int r = 0; r < 4; ++r) {
          const int m = mbase + mi * 16 + lg * 4 + r;
          const size_t idx = (size_t)m * N + n;
          o[idx] = f2bf(acc[mi][ni][r] + bv + extraF[idx]);
        }
    }
  } else if constexpr (EPI == EPI_FF) {
    short* o = (short*)outp;
#pragma unroll
    for (int ni = 0; ni < 4; ++ni) {
      const int n = nbase + ni * 16 + l16;
      const float bv = bias[n];
#pragma unroll
      for (int mi = 0; mi < 4; ++mi)
#pragma unroll
        for (int r = 0; r < 4; ++r) {
          const int m = mbase + mi * 16 + lg * 4 + r;
          const size_t idx = (size_t)m * N + n;
          o[idx] = f2bf(acc[mi][ni][r] + bv + bf2f(extraB[idx]));
        }
    }
  } else {  // EPI_RELU -> bf16
    short* o = (short*)outp;
#pragma unroll
    for (int ni = 0; ni < 4; ++ni) {
      const int n = nbase + ni * 16 + l16;
      const float bv = bias[n];
#pragma unroll
      for (int mi = 0; mi < 4; ++mi)
#pragma unroll
        for (int r = 0; r < 4; ++r) {
          const int m = mbase + mi * 16 + lg * 4 + r;
          o[(size_t)m * N + n] = f2bf(fmaxf(acc[mi][ni][r] + bv, 0.f));
        }
    }
  }
}

// ---------------- flash attention v7: barrier-free, fragment-direct, KV-split ----
// No LDS, no __syncthreads. Each wave owns a 64-q strip; K/V fragments are read
// as coalesced 1KB blocks from the frag-major buffers (L2-resident per XCD).
// Unroll-2 K double-buffer in registers; constant-shift softmax; f32 partials.
__global__ __launch_bounds__(256) void attn_fa7(
    const short* __restrict__ Q,    // [BH,S,64] pre-scaled by 0.125*log2e
    const short* __restrict__ Kf,   // frag-major
    const short* __restrict__ Vf,   // frag-major
    const int* __restrict__ mask,   // [B,S]
    float* __restrict__ opart,      // [2][BH][S][64] unnormalized
    float* __restrict__ lpart) {    // [2][BH][S]
  const int tid = threadIdx.x;
  const int lane = tid & 63, w = tid >> 6;
  const int l31 = lane & 31, hi = lane >> 5;

  // XCD-chunked remap (same as r7): all q-blocks of one (bh,half) on one XCD
  const int i = blockIdx.x;               // [0,768)
  const int r8 = i & 7, qq = i >> 3;
  const int bhz = ((qq >> 3) << 3) + r8;  // [0,96)
  const int qblk = qq & 7;
  const int half = bhz / 48, bh = bhz % 48;
  const int b = bh / NHEADS;
  const int q0 = qblk * 256 + w * 64;
  const int kvt0 = half * 32;             // 32-kv tile index base

  // Q B-fragments for both 32-col groups
  const short* qpA = Q + ((size_t)bh * SEQ + q0 + l31) * 64;
  const short* qpB = qpA + 32 * 64;
  short8 qfA[4], qfB[4];
#pragma unroll
  for (int s = 0; s < 4; ++s) {
    qfA[s] = *(const short8*)(qpA + s * 16 + hi * 8);
    qfB[s] = *(const short8*)(qpB + s * 16 + hi * 8);
  }

  // per-lane fragment base pointers (each frag = 512 elems = 1KB apart)
  const short* kfb = Kf + (((size_t)bh * 64 + kvt0) * 4 * 64 + lane) * 8;
  const short* vfb = Vf + (((size_t)bh * 128 + kvt0 * 2) * 2 * 64 + lane) * 8;
  const int* mrow = mask + (size_t)b * SEQ + kvt0 * 32;

  f32x16 o0a, o1a, o0b, o1b;
#pragma unroll
  for (int k = 0; k < 16; ++k) { o0a[k] = 0.f; o1a[k] = 0.f; o0b[k] = 0.f; o1b[k] = 0.f; }
  float raA = 0.f, raB = 0.f;

  short8 kfX[4], kfY[4];
#pragma unroll
  for (int s = 0; s < 4; ++s) kfX[s] = *(const short8*)(kfb + (size_t)s * 512);

  auto body = [&](int t, short8* kcur, short8* knext) {
    // V(t) fragments: issue early, consumed by PV at body end
    short8 vf[4];
#pragma unroll
    for (int j = 0; j < 4; ++j)
      vf[j] = *(const short8*)(vfb + ((size_t)t * 4 + j) * 512);

    // S^T = K Q for both q-groups (32 kv x 32 q each)
    f32x16 sa, sb;
#pragma unroll
    for (int k = 0; k < 16; ++k) { sa[k] = 0.f; sb[k] = 0.f; }
#pragma unroll
    for (int s = 0; s < 4; ++s) {
      sa = __builtin_amdgcn_mfma_f32_32x32x16_bf16(kcur[s], qfA[s], sa, 0, 0, 0);
      sb = __builtin_amdgcn_mfma_f32_32x32x16_bf16(kcur[s], qfB[s], sb, 0, 0, 0);
    }

    // prefetch K(t+1) into the alternate buffer (last iter over-reads into Vf; unused)
#pragma unroll
    for (int s = 0; s < 4; ++s)
      knext[s] = *(const short8*)(kfb + ((size_t)(t + 1) * 4 + s) * 512);

    // mask (rare path)
    const int mv = mrow[t * 32 + l31];
    if (__any(mv == 0)) {
#pragma unroll
      for (int r = 0; r < 16; ++r) {
        const int cr = (r & 3) + 8 * (r >> 2) + 4 * hi;
        if (__shfl(mv, cr) == 0) { sa[r] = -1e9f; sb[r] = -1e9f; }
      }
    }

    // P = exp2(s) (constant-shift softmax), per-lane rowsum accumulation
#pragma unroll
    for (int r = 0; r < 16; ++r) {
      sa[r] = fexp2(sa[r]);
      sb[r] = fexp2(sb[r]);
      raA += sa[r];
      raB += sb[r];
    }

    // pack P -> bf16 A-frags (2 kv-16 slices per group)
    short8 paA[2], paB[2];
#pragma unroll
    for (int ks = 0; ks < 2; ++ks) {
      const int rb0 = ks * 8;
#pragma unroll
      for (int g = 0; g < 2; ++g) {
        const f32x16& sc = g ? sb : sa;
        int x0_ = cvtpk(sc[rb0 + 0], sc[rb0 + 1]);
        int y0_ = cvtpk(sc[rb0 + 4], sc[rb0 + 5]);
        int x1_ = cvtpk(sc[rb0 + 2], sc[rb0 + 3]);
        int y1_ = cvtpk(sc[rb0 + 6], sc[rb0 + 7]);
        int4v pw;
#if __has_builtin(__builtin_amdgcn_permlane32_swap)
        int2v r0 = __builtin_amdgcn_permlane32_swap(x0_, y0_, false, false);
        int2v r1 = __builtin_amdgcn_permlane32_swap(x1_, y1_, false, false);
        pw[0] = r0[0]; pw[1] = r1[0]; pw[2] = r0[1]; pw[3] = r1[1];
#else
        const int ys0 = __shfl_xor(y0_, 32);
        const int xs0 = __shfl_xor(x0_, 32);
        const int ys1 = __shfl_xor(y1_, 32);
        const int xs1 = __shfl_xor(x1_, 32);
        pw[0] = hi ? ys0 : x0_;
        pw[1] = hi ? ys1 : x1_;
        pw[2] = hi ? y0_ : xs0;
        pw[3] = hi ? y1_ : xs1;
#endif
        const short8 pa = __builtin_bit_cast(short8, pw);
        if (g) paB[ks] = pa; else paA[ks] = pa;
      }
    }

    // PV: vf[ks*2+dblk] feeds both q-groups
#pragma unroll
    for (int ks = 0; ks < 2; ++ks) {
      o0a = __builtin_amdgcn_mfma_f32_32x32x16_bf16(paA[ks], vf[ks * 2 + 0], o0a, 0, 0, 0);
      o0b = __builtin_amdgcn_mfma_f32_32x32x16_bf16(paB[ks], vf[ks * 2 + 0], o0b, 0, 0, 0);
      o1a = __builtin_amdgcn_mfma_f32_32x32x16_bf16(paA[ks], vf[ks * 2 + 1], o1a, 0, 0, 0);
      o1b = __builtin_amdgcn_mfma_f32_32x32x16_bf16(paB[ks], vf[ks * 2 + 1], o1b, 0, 0, 0);
    }
  };

  for (int tt = 0; tt < 16; ++tt) {
    body(2 * tt, kfX, kfY);
    body(2 * tt + 1, kfY, kfX);
  }

  const float lA = raA + __shfl_xor(raA, 32);
  const float lB = raB + __shfl_xor(raB, 32);

  // ---- epilogue: unnormalized f32 partials ----
  float* opA = opart + ((size_t)half * BATCH * NHEADS + bh) * SEQ * 64;
#pragma unroll
  for (int r = 0; r < 16; ++r) {
    const int q = (r & 3) + 8 * (r >> 2) + 4 * hi;
    float* pa_ = opA + (size_t)(q0 + q) * 64;
    pa_[l31] = o0a[r];
    pa_[32 + l31] = o1a[r];
    float* pb_ = opA + (size_t)(q0 + 32 + q) * 64;
    pb_[l31] = o0b[r];
    pb_[32 + l31] = o1b[r];
  }
  if (lane < 32) {
    float* lp = lpart + (size_t)half * BATCH * NHEADS * SEQ + (size_t)bh * SEQ + q0;
    lp[l31] = lA;
    lp[32 + l31] = lB;
  }
}

// ---------------- combine: ctx = (O0+O1)/(l0+l1), bf16 ----------------
__global__ __launch_bounds__(256) void attn_combine(const float* __restrict__ op,
                                                    const float* __restrict__ lp,
                                                    short* __restrict__ ctx) {
  const size_t HS = (size_t)BATCH * NHEADS * SEQ * 64;  // elems per half
  const int i4 = blockIdx.x * 256 + threadIdx.x;        // float4 units
  const size_t base = (size_t)i4 * 4;
  float4v a = *(const float4v*)(op + base);
  float4v c = *(const float4v*)(op + HS + base);
  const int row = (int)(base >> 6);                     // bh*SEQ + q
  const float inv = frcp(lp[row] + lp[BATCH * NHEADS * SEQ + row]);
  const int bh = row >> 11, q = row & 2047;
  const int b = bh / NHEADS, h = bh - b * NHEADS;
  const int dk = (int)(base & 63);
  ushort4v o;
#pragma unroll
  for (int j = 0; j < 4; ++j) o[j] = (unsigned short)f2bf((a[j] + c[j]) * inv);
  *(ushort4v*)(ctx + ((size_t)b * SEQ + q) * D_MODEL + h * 64 + dk) = o;
}

// ---------------- LayerNorm: one wave per row, bf16 in, bf16/f32 out ----------------
template <int OUT_F32>
__global__ __launch_bounds__(256) void ln_w(const short* __restrict__ y,
                                            const float* __restrict__ gw,
                                            const float* __restrict__ bw,
                                            float* __restrict__ of,
                                            short* __restrict__ ob) {
  const int lane = threadIdx.x & 63, w = threadIdx.x >> 6;
  const int row = blockIdx.x * 4 + w;
  const short* yr = y + (size_t)row * D_MODEL;
  short8 v8 = *(const short8*)(yr + lane * 8);
  ushort4v v4 = *(const ushort4v*)(yr + 512 + lane * 4);
  float f[12];
#pragma unroll
  for (int j = 0; j < 8; ++j) f[j] = bf2f(v8[j]);
#pragma unroll
  for (int j = 0; j < 4; ++j) f[8 + j] = bf2f((short)v4[j]);
  float s = 0.f, q = 0.f;
#pragma unroll
  for (int j = 0; j < 12; ++j) { s += f[j]; q += f[j] * f[j]; }
#pragma unroll
  for (int mm = 1; mm < 64; mm <<= 1) {
    s += __shfl_xor(s, mm);
    q += __shfl_xor(q, mm);
  }
  const float mu = s * (1.f / D_MODEL);
  const float rs = rsqrtf(q * (1.f / D_MODEL) - mu * mu + 1e-5f);
  float4v g0 = *(const float4v*)(gw + lane * 8);
  float4v g1 = *(const float4v*)(gw + lane * 8 + 4);
  float4v g2 = *(const float4v*)(gw + 512 + lane * 4);
  float4v b0 = *(const float4v*)(bw + lane * 8);
  float4v b1 = *(const float4v*)(bw + lane * 8 + 4);
  float4v b2 = *(const float4v*)(bw + 512 + lane * 4);
  float o[12];
#pragma unroll
  for (int j = 0; j < 4; ++j) o[j] = (f[j] - mu) * rs * g0[j] + b0[j];
#pragma unroll
  for (int j = 0; j < 4; ++j) o[4 + j] = (f[4 + j] - mu) * rs * g1[j] + b1[j];
#pragma unroll
  for (int j = 0; j < 4; ++j) o[8 + j] = (f[8 + j] - mu) * rs * g2[j] + b2[j];
  if constexpr (OUT_F32) {
    float* orow = of + (size_t)row * D_MODEL;
    float4v t0, t1, t2;
#pragma unroll
    for (int j = 0; j < 4; ++j) { t0[j] = o[j]; t1[j] = o[4 + j]; t2[j] = o[8 + j]; }
    *(float4v*)(orow + lane * 8) = t0;
    *(float4v*)(orow + lane * 8 + 4) = t1;
    *(float4v*)(orow + 512 + lane * 4) = t2;
  } else {
    short* orow = ob + (size_t)row * D_MODEL;
    ushort4v t0, t1, t2;
#pragma unroll
    for (int j = 0; j < 4; ++j) {
      t0[j] = (unsigned short)f2bf(o[j]);
      t1[j] = (unsigned short)f2bf(o[4 + j]);
      t2[j] = (unsigned short)f2bf(o[8 + j]);
    }
    *(ushort4v*)(orow + lane * 8) = t0;
    *(ushort4v*)(orow + lane * 8 + 4) = t1;
    *(ushort4v*)(orow + 512 + lane * 4) = t2;
  }
}

// ---------------- launch ----------------
extern "C" void kernel_launch(void* const* d_in, const int* in_sizes, int n_in,
                              void* d_out, int out_size, void* d_ws, size_t ws_size,
                              hipStream_t stream) {
  const float* emb = (const float*)d_in[0];
  const int* mask = (const int*)d_in[1];
  const float* Wq = (const float*)d_in[2];
  const float* bq = (const float*)d_in[3];
  const float* Wk = (const float*)d_in[4];
  const float* bk = (const float*)d_in[5];
  const float* Wv = (const float*)d_in[6];
  const float* bv = (const float*)d_in[7];
  const float* Wo = (const float*)d_in[8];
  const float* bo = (const float*)d_in[9];
  const float* W1 = (const float*)d_in[10];
  const float* b1 = (const float*)d_in[11];
  const float* W2 = (const float*)d_in[12];
  const float* b2 = (const float*)d_in[13];
  const float* lng = (const float*)d_in[14];
  const float* lnb = (const float*)d_in[15];

  char* ws = (char*)d_ws;
  size_t off = 0;
  auto alloc = [&](size_t bytes) -> char* {
    char* p = ws + off;
    off = (off + bytes + 255) & ~(size_t)255;
    return p;
  };
  const size_t DD = (size_t)D_MODEL * D_MODEL;
  const size_t DF = (size_t)D_MODEL * FF_DIM;
  const size_t TD = (size_t)NTOK * D_MODEL;
  const size_t TF = (size_t)NTOK * FF_DIM;

  short* wqkvt = (short*)alloc(3 * DD * 2);
  short* wot = (short*)alloc(DD * 2);
  short* w1t = (short*)alloc(DF * 2);
  short* w2t = (short*)alloc(DF * 2);
  float* bqkv = (float*)alloc(2304 * 4);
  short* x0 = (short*)alloc(TD * 2);     // emb bf16; reused as ctx after QKV
  short* qkv = (short*)alloc(3 * TD * 2);
  short* aresb = (short*)alloc(TD * 2);
  short* xbf = (short*)alloc(TD * 2);
  short* hbf = (short*)alloc(TF * 2);    // FF hidden; ALSO aliased as opart before FF
  short* ffresb = (short*)alloc(TD * 2);
  float* lpart = (float*)alloc(2 * (size_t)BATCH * NHEADS * SEQ * 4);
  short* qb = qkv;
  short* kfr = qkv + TD;                 // K fragment-major
  short* vfr = qkv + 2 * TD;             // V fragment-major
  short* ctx = x0;
  float* opart = (float*)hbf;  // 50.3MB == TF*2 bytes; dead before FF1

  prep<<<dim3(1729 + (int)(TD / 1024)), 256, 0, stream>>>(
      Wq, Wk, Wv, Wo, W1, W2, bq, bk, bv, emb, wqkvt, wot, w1t, w2t, bqkv, x0);
  gemm_bt<EPI_QKV><<<dim3(18, 64), 256, 0, stream>>>(
      x0, wqkvt, bqkv, nullptr, nullptr, qkv, NTOK, 3 * D_MODEL, D_MODEL);
  attn_fa7<<<dim3(768), 256, 0, stream>>>(qb, kfr, vfr, mask, opart, lpart);
  attn_combine<<<dim3((int)((size_t)BATCH * NHEADS * SEQ * 64 / 4 / 256)), 256, 0, stream>>>(
      opart, lpart, ctx);
  gemm_bt<EPI_WO><<<dim3(6, 64), 256, 0, stream>>>(
      ctx, wot, bo, emb, nullptr, aresb, NTOK, D_MODEL, D_MODEL);
  ln_w<0><<<dim3(NTOK / 4), 256, 0, stream>>>(aresb, lng, lnb, nullptr, xbf);
  gemm_bt<EPI_RELU><<<dim3(24, 64), 256, 0, stream>>>(
      xbf, w1t, b1, nullptr, nullptr, hbf, NTOK, FF_DIM, D_MODEL);
  gemm_bt<EPI_FF><<<dim3(6, 64), 256, 0, stream>>>(
      hbf, w2t, b2, nullptr, xbf, ffresb, NTOK, D_MODEL, FF_DIM);
  ln_w<1><<<dim3(NTOK / 4), 256, 0, stream>>>(ffresb, lng, lnb, (float*)d_out, nullptr);
}

// Round 9
// 289.293 us; speedup vs baseline: 1.0803x; 1.0803x over previous
//
#include <hip/hip_runtime.h>

#define D_MODEL 768
#define NHEADS  12
#define SEQ     2048
#define BATCH   4
#define FF_DIM  3072
#define NTOK    (BATCH * SEQ)

typedef short short8 __attribute__((ext_vector_type(8)));
typedef float f32x4 __attribute__((ext_vector_type(4)));
typedef float f32x16 __attribute__((ext_vector_type(16)));
typedef int int4v __attribute__((ext_vector_type(4)));
typedef int int2v __attribute__((ext_vector_type(2)));
typedef unsigned short ushort4v __attribute__((ext_vector_type(4)));
typedef float float4v __attribute__((ext_vector_type(4)));

__device__ __forceinline__ short f2bf(float x) {
  unsigned u = __builtin_bit_cast(unsigned, x);
  u += 0x7fffu + ((u >> 16) & 1u);   // RNE
  return (short)(u >> 16);
}
__device__ __forceinline__ float bf2f(short x) {
  return __builtin_bit_cast(float, ((unsigned)(unsigned short)x) << 16);
}
__device__ __forceinline__ int cvtpk(float a, float b) {
  int r;
  asm("v_cvt_pk_bf16_f32 %0, %1, %2" : "=v"(r) : "v"(a), "v"(b));
  return r;  // lo16 = bf16(a), hi16 = bf16(b)
}
__device__ __forceinline__ float fexp2(float x) {
#if __has_builtin(__builtin_amdgcn_exp2f)
  return __builtin_amdgcn_exp2f(x);   // single v_exp_f32
#else
  return exp2f(x);
#endif
}
__device__ __forceinline__ float frcp(float x) {
#if __has_builtin(__builtin_amdgcn_rcpf)
  return __builtin_amdgcn_rcpf(x);    // single v_rcp_f32
#else
  return 1.f / x;
#endif
}
__device__ __forceinline__ void gll16(const void* g, void* l) {
  __builtin_amdgcn_global_load_lds(
      (const __attribute__((address_space(1))) void*)g,
      (__attribute__((address_space(3))) void*)l, 16, 0, 0);
}

// ---------------- prep: all weight transposes + bias concat + emb cast ----------------
__device__ __forceinline__ void wt_tile(float (*T)[65], const float* __restrict__ W,
                                        short* __restrict__ Wt, int K, int N,
                                        int bx, int by, int t) {
  const int c = t & 63, rb = t >> 6;
  const int k0 = by * 64, n0 = bx * 64;
#pragma unroll
  for (int i = 0; i < 16; ++i) {
    const int r = rb * 16 + i;
    T[c][r] = W[(size_t)(k0 + r) * N + n0 + c];
  }
  __syncthreads();
#pragma unroll
  for (int j = 0; j < 16; ++j) {
    const int idx = t + j * 256;
    const int nl = idx >> 6, kl = idx & 63;
    Wt[(size_t)(n0 + nl) * K + k0 + kl] = f2bf(T[nl][kl]);
  }
}

__global__ __launch_bounds__(256) void prep(
    const float* __restrict__ Wq, const float* __restrict__ Wk, const float* __restrict__ Wv,
    const float* __restrict__ Wo, const float* __restrict__ W1, const float* __restrict__ W2,
    const float* __restrict__ bq, const float* __restrict__ bk, const float* __restrict__ bv,
    const float* __restrict__ emb,
    short* __restrict__ wqkvt, short* __restrict__ wot, short* __restrict__ w1t,
    short* __restrict__ w2t, float* __restrict__ bqkv, short* __restrict__ x0) {
  __shared__ float T[64][65];
  const int bi = blockIdx.x;
  const int t = threadIdx.x;
  if (bi < 432) {
    const int s = bi / 144, l = bi % 144;
    const float* W = (s == 0) ? Wq : (s == 1) ? Wk : Wv;
    wt_tile(T, W, wqkvt + (size_t)s * 768 * 768, 768, 768, l % 12, l / 12, t);
  } else if (bi < 576) {
    const int l = bi - 432;
    wt_tile(T, Wo, wot, 768, 768, l % 12, l / 12, t);
  } else if (bi < 1152) {
    const int l = bi - 576;
    wt_tile(T, W1, w1t, 768, 3072, l % 48, l / 48, t);
  } else if (bi < 1728) {
    const int l = bi - 1152;
    wt_tile(T, W2, w2t, 3072, 768, l % 12, l / 12, t);
  } else if (bi == 1728) {
#pragma unroll
    for (int j = 0; j < 9; ++j) {
      const int i = t + j * 256;
      bqkv[i] = (i < 768) ? bq[i] : (i < 1536) ? bk[i - 768] : bv[i - 1536];
    }
  } else {
    const int i = (bi - 1729) * 256 + t;
    float4v v = *(const float4v*)(emb + (size_t)i * 4);
    ushort4v p;
    p[0] = (unsigned short)f2bf(v[0]);
    p[1] = (unsigned short)f2bf(v[1]);
    p[2] = (unsigned short)f2bf(v[2]);
    p[3] = (unsigned short)f2bf(v[3]);
    *(ushort4v*)(x0 + (size_t)i * 4) = p;
  }
}

// ---------------- GEMM 128x128: C = A x Bt^T, fused epilogues ----------------
enum { EPI_QKV = 0, EPI_WO = 1, EPI_RELU = 2, EPI_FF = 3 };

template <int EPI>
__global__ __launch_bounds__(256) void gemm_bt(const short* __restrict__ A,
                                               const short* __restrict__ Bt,
                                               const float* __restrict__ bias,
                                               const float* __restrict__ extraF,
                                               const short* __restrict__ extraB,
                                               void* __restrict__ outp,
                                               int M, int N, int K) {
  __shared__ short As[128 * 64];
  __shared__ short Bs[128 * 64];
  const int tid = threadIdx.x;
  const int lane = tid & 63, wid = tid >> 6;
  const int wr = wid >> 1, wc = wid & 1;
  const int l16 = lane & 15, lg = lane >> 4;
  const int brow = blockIdx.y * 128, bcol = blockIdx.x * 128;

  f32x4 acc[4][4];
#pragma unroll
  for (int i = 0; i < 4; ++i)
#pragma unroll
    for (int j = 0; j < 4; ++j) acc[i][j] = (f32x4){0.f, 0.f, 0.f, 0.f};

  for (int kt = 0; kt < K; kt += 64) {
    __syncthreads();
#pragma unroll
    for (int i = 0; i < 4; ++i) {
      const int c = wid * 256 + i * 64 + lane;
      const int row = c >> 3;
      const int gc = (c & 7) ^ (row & 7);           // pre-swizzled global source
      gll16(A + (size_t)(brow + row) * K + kt + gc * 8,
            (char*)As + (wid * 256 + i * 64) * 16);
      gll16(Bt + (size_t)(bcol + row) * K + kt + gc * 8,
            (char*)Bs + (wid * 256 + i * 64) * 16);
    }
    __syncthreads();
#pragma unroll
    for (int kc = 0; kc < 2; ++kc) {
      short8 af[4], bfr[4];
#pragma unroll
      for (int m = 0; m < 4; ++m) {
        const int row = wr * 64 + m * 16 + l16;
        const int ch = (kc * 4 + lg) ^ (row & 7);
        af[m] = *(const short8*)((const char*)As + row * 128 + ch * 16);
      }
#pragma unroll
      for (int n = 0; n < 4; ++n) {
        const int row = wc * 64 + n * 16 + l16;
        const int ch = (kc * 4 + lg) ^ (row & 7);
        bfr[n] = *(const short8*)((const char*)Bs + row * 128 + ch * 16);
      }
#pragma unroll
      for (int m = 0; m < 4; ++m)
#pragma unroll
        for (int n = 0; n < 4; ++n)
          acc[m][n] = __builtin_amdgcn_mfma_f32_16x16x32_bf16(af[m], bfr[n],
                                                              acc[m][n], 0, 0, 0);
    }
  }

  const int mbase = brow + wr * 64;
  const int nbase = bcol + wc * 64;

  if constexpr (EPI == EPI_QKV) {
    short* qb_ = (short*)outp;
    short* kb_ = qb_ + (size_t)NTOK * D_MODEL;
    short* vt_ = kb_ + (size_t)NTOK * D_MODEL;
    const int type = nbase / 768;  // block-uniform
#pragma unroll
    for (int ni = 0; ni < 4; ++ni) {
      const int n = nbase + ni * 16 + l16;
      const float bv = bias[n];
      const int ncol = n - type * 768;
      const int h = ncol >> 6, dk = ncol & 63;
      if (type == 2) {  // V: transposed store [bh][dk][s]
#pragma unroll
        for (int mi = 0; mi < 4; ++mi) {
          const int m0 = mbase + mi * 16 + lg * 4;
          const int bidx = m0 >> 11, s0 = m0 & 2047;
          ushort4v pk;
#pragma unroll
          for (int r = 0; r < 4; ++r) pk[r] = (unsigned short)f2bf(acc[mi][ni][r] + bv);
          *(ushort4v*)(vt_ + (((size_t)bidx * NHEADS + h) * 64 + dk) * SEQ + s0) = pk;
        }
      } else {
        short* o = (type == 0) ? qb_ : kb_;
        const float sc = (type == 0) ? 0.125f * 1.44269504f : 1.f;  // Q: 1/sqrt(DK)*log2e
#pragma unroll
        for (int mi = 0; mi < 4; ++mi) {
#pragma unroll
          for (int r = 0; r < 4; ++r) {
            const int m = mbase + mi * 16 + lg * 4 + r;
            const int bidx = m >> 11, sidx = m & 2047;
            o[(((size_t)bidx * NHEADS + h) * SEQ + sidx) * 64 + dk] =
                f2bf((acc[mi][ni][r] + bv) * sc);
          }
        }
      }
    }
  } else {  // EPI_RELU -> bf16 (only other 128x128 user)
    short* o = (short*)outp;
#pragma unroll
    for (int ni = 0; ni < 4; ++ni) {
      const int n = nbase + ni * 16 + l16;
      const float bv = bias[n];
#pragma unroll
      for (int mi = 0; mi < 4; ++mi)
#pragma unroll
        for (int r = 0; r < 4; ++r) {
          const int m = mbase + mi * 16 + lg * 4 + r;
          o[(size_t)m * N + n] = f2bf(fmaxf(acc[mi][ni][r] + bv, 0.f));
        }
    }
  }
}

// ---------------- GEMM 128x64 (BN=64): for N=768 GEMMs (WO, FF2) ----------------
// grid (N/64, M/128) = 768 blocks -> 3 blocks/CU inter-block latency hiding
// (the 128x128 version gave only 384 blocks = 1.5/CU for these shapes).
template <int EPI>
__global__ __launch_bounds__(256) void gemm_bn64(const short* __restrict__ A,
                                                 const short* __restrict__ Bt,
                                                 const float* __restrict__ bias,
                                                 const float* __restrict__ extraF,
                                                 const short* __restrict__ extraB,
                                                 void* __restrict__ outp,
                                                 int M, int N, int K) {
  __shared__ short As[128 * 64];
  __shared__ short Bs[64 * 64];
  const int tid = threadIdx.x;
  const int lane = tid & 63, wid = tid >> 6;
  const int l16 = lane & 15, lg = lane >> 4;
  const int brow = blockIdx.y * 128, bcol = blockIdx.x * 64;

  f32x4 acc[2][4];
#pragma unroll
  for (int i = 0; i < 2; ++i)
#pragma unroll
    for (int j = 0; j < 4; ++j) acc[i][j] = (f32x4){0.f, 0.f, 0.f, 0.f};

  for (int kt = 0; kt < K; kt += 64) {
    __syncthreads();
#pragma unroll
    for (int i = 0; i < 4; ++i) {  // A: 4 chunks/thread
      const int c = wid * 256 + i * 64 + lane;
      const int row = c >> 3;
      const int gc = (c & 7) ^ (row & 7);
      gll16(A + (size_t)(brow + row) * K + kt + gc * 8,
            (char*)As + (wid * 256 + i * 64) * 16);
    }
#pragma unroll
    for (int i = 0; i < 2; ++i) {  // B: 2 chunks/thread
      const int c = i * 256 + tid;
      const int row = c >> 3;
      const int gc = (c & 7) ^ (row & 7);
      gll16(Bt + (size_t)(bcol + row) * K + kt + gc * 8,
            (char*)Bs + (i * 256 + wid * 64) * 16);
    }
    __syncthreads();
#pragma unroll
    for (int kc = 0; kc < 2; ++kc) {
      short8 af[2], bfr[4];
#pragma unroll
      for (int m = 0; m < 2; ++m) {
        const int row = wid * 32 + m * 16 + l16;
        const int ch = (kc * 4 + lg) ^ (row & 7);
        af[m] = *(const short8*)((const char*)As + row * 128 + ch * 16);
      }
#pragma unroll
      for (int n = 0; n < 4; ++n) {
        const int row = n * 16 + l16;
        const int ch = (kc * 4 + lg) ^ (row & 7);
        bfr[n] = *(const short8*)((const char*)Bs + row * 128 + ch * 16);
      }
#pragma unroll
      for (int m = 0; m < 2; ++m)
#pragma unroll
        for (int n = 0; n < 4; ++n)
          acc[m][n] = __builtin_amdgcn_mfma_f32_16x16x32_bf16(af[m], bfr[n],
                                                              acc[m][n], 0, 0, 0);
    }
  }

  const int mbase = brow + wid * 32;
#pragma unroll
  for (int ni = 0; ni < 4; ++ni) {
    const int n = bcol + ni * 16 + l16;
    const float bv = bias[n];
#pragma unroll
    for (int mi = 0; mi < 2; ++mi)
#pragma unroll
      for (int r = 0; r < 4; ++r) {
        const int m = mbase + mi * 16 + lg * 4 + r;
        const size_t idx = (size_t)m * N + n;
        if constexpr (EPI == EPI_WO) {
          ((short*)outp)[idx] = f2bf(acc[mi][ni][r] + bv + extraF[idx]);
        } else {  // EPI_FF
          ((short*)outp)[idx] = f2bf(acc[mi][ni][r] + bv + bf2f(extraB[idx]));
        }
      }
  }
}

// ---------------- flash attention: LDS-staged + KV-split + XCD-chunked + setprio ----
__global__ __launch_bounds__(256) void attn_fa6(
    const short* __restrict__ Q,   // [BH,S,64] pre-scaled by 0.125*log2e
    const short* __restrict__ Kb,  // [BH,S,64]
    const short* __restrict__ Vt,  // [BH,64,S]
    const int* __restrict__ mask,  // [B,S]
    float* __restrict__ opart,     // [2][BH][S][64] unnormalized
    float* __restrict__ lpart) {   // [2][BH][S]
  __shared__ short KsA[64 * 64], KsB[64 * 64];
  __shared__ short VsA[64 * 64], VsB[64 * 64];
  const int tid = threadIdx.x;
  const int lane = tid & 63, w = tid >> 6;
  const int l31 = lane & 31, hi = lane >> 5;

  // XCD-chunked remap: all 8 q-blocks of one (bh,half) on one XCD
  const int i = blockIdx.x;               // [0,768)
  const int r8 = i & 7, qq = i >> 3;
  const int bhz = ((qq >> 3) << 3) + r8;  // [0,96)
  const int qblk = qq & 7;
  const int half = bhz / 48, bh = bhz % 48;
  const int b = bh / NHEADS;
  const int q0 = qblk * 256 + w * 64;
  const int kvbase = half * (SEQ / 2);

  const short* qpA = Q + ((size_t)bh * SEQ + q0 + l31) * 64;
  const short* qpB = qpA + 32 * 64;
  short8 qfA[4], qfB[4];
#pragma unroll
  for (int s = 0; s < 4; ++s) {
    qfA[s] = *(const short8*)(qpA + s * 16 + hi * 8);
    qfB[s] = *(const short8*)(qpB + s * 16 + hi * 8);
  }

  f32x16 o0a, o1a, o0b, o1b;
#pragma unroll
  for (int k = 0; k < 16; ++k) { o0a[k] = 0.f; o1a[k] = 0.f; o0b[k] = 0.f; o1b[k] = 0.f; }
  float lA = 0.f, lB = 0.f;  // per-lane; cross-half reduce deferred to epilogue

  auto stage = [&](short* Ksd, short* Vsd, int kv0) {
#pragma unroll
    for (int i2 = 0; i2 < 2; ++i2) {
      const int c = i2 * 256 + tid;
      const int row = c >> 3;
      const int gc = (c & 7) ^ (row & 7);  // pre-swizzled source, linear LDS dest
      gll16(Kb + ((size_t)bh * SEQ + kv0 + row) * 64 + gc * 8,
            (char*)Ksd + (i2 * 256 + w * 64) * 16);
      gll16(Vt + ((size_t)bh * 64 + row) * SEQ + kv0 + gc * 8,
            (char*)Vsd + (i2 * 256 + w * 64) * 16);
    }
  };

  stage(KsA, VsA, kvbase);
  __syncthreads();

  for (int t = 0; t < SEQ / 2 / 64; ++t) {
    const short* Ksc = (t & 1) ? KsB : KsA;
    const short* Vsc = (t & 1) ? VsB : VsA;

    const int mv = mask[(size_t)b * SEQ + kvbase + t * 64 + lane];
    const bool anym = __any(mv == 0);
    short8 paA[4], paB[4];

#pragma unroll
    for (int ph = 0; ph < 2; ++ph) {
      f32x16 sa, sb;
#pragma unroll
      for (int k = 0; k < 16; ++k) { sa[k] = 0.f; sb[k] = 0.f; }
      const char* kr = (const char*)Ksc + (ph * 32 + l31) * 128;
      __builtin_amdgcn_s_setprio(1);
#pragma unroll
      for (int slot = 0; slot < 4; ++slot) {
        const int ch = (slot * 2 + hi) ^ (l31 & 7);
        short8 kf = *(const short8*)(kr + ch * 16);
        sa = __builtin_amdgcn_mfma_f32_32x32x16_bf16(kf, qfA[slot], sa, 0, 0, 0);
        sb = __builtin_amdgcn_mfma_f32_32x32x16_bf16(kf, qfB[slot], sb, 0, 0, 0);
      }
      __builtin_amdgcn_s_setprio(0);
      if (ph == 1 && t + 1 < SEQ / 2 / 64)  // stage next tile; lands during sm+PV
        stage((t & 1) ? KsA : KsB, (t & 1) ? VsA : VsB, kvbase + (t + 1) * 64);
      if (anym) {
#pragma unroll
        for (int r = 0; r < 16; ++r) {
          const int cr = ph * 32 + (r & 3) + 8 * (r >> 2) + 4 * hi;
          if (__shfl(mv, cr) == 0) { sa[r] = -1e9f; sb[r] = -1e9f; }
        }
      }
#pragma unroll
      for (int r = 0; r < 16; ++r) {
        sa[r] = fexp2(sa[r]);
        sb[r] = fexp2(sb[r]);
        lA += sa[r];
        lB += sb[r];
      }
      // pack P -> bf16 A-frags (cvt_pk + lane^32 swap)
#pragma unroll
      for (int ks = 0; ks < 2; ++ks) {
        const int rb0 = ks * 8;
#pragma unroll
        for (int g = 0; g < 2; ++g) {
          const f32x16& sc = g ? sb : sa;
          int x0_ = cvtpk(sc[rb0 + 0], sc[rb0 + 1]);
          int y0_ = cvtpk(sc[rb0 + 4], sc[rb0 + 5]);
          int x1_ = cvtpk(sc[rb0 + 2], sc[rb0 + 3]);
          int y1_ = cvtpk(sc[rb0 + 6], sc[rb0 + 7]);
          int4v pw;
#if __has_builtin(__builtin_amdgcn_permlane32_swap)
          int2v r0 = __builtin_amdgcn_permlane32_swap(x0_, y0_, false, false);
          int2v r1 = __builtin_amdgcn_permlane32_swap(x1_, y1_, false, false);
          pw[0] = r0[0]; pw[1] = r1[0]; pw[2] = r0[1]; pw[3] = r1[1];
#else
          const int ys0 = __shfl_xor(y0_, 32);
          const int xs0 = __shfl_xor(x0_, 32);
          const int ys1 = __shfl_xor(y1_, 32);
          const int xs1 = __shfl_xor(x1_, 32);
          pw[0] = hi ? ys0 : x0_;
          pw[1] = hi ? ys1 : x1_;
          pw[2] = hi ? y0_ : xs0;
          pw[3] = hi ? y1_ : xs1;
#endif
          const short8 pa = __builtin_bit_cast(short8, pw);
          if (g) paB[ph * 2 + ks] = pa; else paA[ph * 2 + ks] = pa;
        }
      }
    }

    // ---- PV from LDS: every V-fragment read feeds both q-groups ----
    __builtin_amdgcn_s_setprio(1);
#pragma unroll
    for (int vs = 0; vs < 4; ++vs) {
      const int vch = (vs * 2 + hi) ^ (l31 & 7);
      short8 vb0 = *(const short8*)((const char*)Vsc + l31 * 128 + vch * 16);
      short8 vb1 = *(const short8*)((const char*)Vsc + (32 + l31) * 128 + vch * 16);
      o0a = __builtin_amdgcn_mfma_f32_32x32x16_bf16(paA[vs], vb0, o0a, 0, 0, 0);
      o0b = __builtin_amdgcn_mfma_f32_32x32x16_bf16(paB[vs], vb0, o0b, 0, 0, 0);
      o1a = __builtin_amdgcn_mfma_f32_32x32x16_bf16(paA[vs], vb1, o1a, 0, 0, 0);
      o1b = __builtin_amdgcn_mfma_f32_32x32x16_bf16(paB[vs], vb1, o1b, 0, 0, 0);
    }
    __builtin_amdgcn_s_setprio(0);
    __syncthreads();
  }

  lA += __shfl_xor(lA, 32);
  lB += __shfl_xor(lB, 32);

  // ---- epilogue: unnormalized f32 partials ----
  float* opA = opart + ((size_t)half * BATCH * NHEADS + bh) * SEQ * 64;
#pragma unroll
  for (int r = 0; r < 16; ++r) {
    const int q = (r & 3) + 8 * (r >> 2) + 4 * hi;
    float* pa_ = opA + (size_t)(q0 + q) * 64;
    pa_[l31] = o0a[r];
    pa_[32 + l31] = o1a[r];
    float* pb_ = opA + (size_t)(q0 + 32 + q) * 64;
    pb_[l31] = o0b[r];
    pb_[32 + l31] = o1b[r];
  }
  if (lane < 32) {
    float* lp = lpart + (size_t)half * BATCH * NHEADS * SEQ + (size_t)bh * SEQ + q0;
    lp[l31] = lA;
    lp[32 + l31] = lB;
  }
}

// ---------------- combine: ctx = (O0+O1)/(l0+l1), bf16 ----------------
__global__ __launch_bounds__(256) void attn_combine(const float* __restrict__ op,
                                                    const float* __restrict__ lp,
                                                    short* __restrict__ ctx) {
  const size_t HS = (size_t)BATCH * NHEADS * SEQ * 64;  // elems per half
  const int i4 = blockIdx.x * 256 + threadIdx.x;        // float4 units
  const size_t base = (size_t)i4 * 4;
  float4v a = *(const float4v*)(op + base);
  float4v c = *(const float4v*)(op + HS + base);
  const int row = (int)(base >> 6);                     // bh*SEQ + q
  const float inv = frcp(lp[row] + lp[BATCH * NHEADS * SEQ + row]);
  const int bh = row >> 11, q = row & 2047;
  const int b = bh / NHEADS, h = bh - b * NHEADS;
  const int dk = (int)(base & 63);
  ushort4v o;
#pragma unroll
  for (int j = 0; j < 4; ++j) o[j] = (unsigned short)f2bf((a[j] + c[j]) * inv);
  *(ushort4v*)(ctx + ((size_t)b * SEQ + q) * D_MODEL + h * 64 + dk) = o;
}

// ---------------- LayerNorm: one wave per row, bf16 in, bf16/f32 out ----------------
template <int OUT_F32>
__global__ __launch_bounds__(256) void ln_w(const short* __restrict__ y,
                                            const float* __restrict__ gw,
                                            const float* __restrict__ bw,
                                            float* __restrict__ of,
                                            short* __restrict__ ob) {
  const int lane = threadIdx.x & 63, w = threadIdx.x >> 6;
  const int row = blockIdx.x * 4 + w;
  const short* yr = y + (size_t)row * D_MODEL;
  short8 v8 = *(const short8*)(yr + lane * 8);
  ushort4v v4 = *(const ushort4v*)(yr + 512 + lane * 4);
  float f[12];
#pragma unroll
  for (int j = 0; j < 8; ++j) f[j] = bf2f(v8[j]);
#pragma unroll
  for (int j = 0; j < 4; ++j) f[8 + j] = bf2f((short)v4[j]);
  float s = 0.f, q = 0.f;
#pragma unroll
  for (int j = 0; j < 12; ++j) { s += f[j]; q += f[j] * f[j]; }
#pragma unroll
  for (int mm = 1; mm < 64; mm <<= 1) {
    s += __shfl_xor(s, mm);
    q += __shfl_xor(q, mm);
  }
  const float mu = s * (1.f / D_MODEL);
  const float rs = rsqrtf(q * (1.f / D_MODEL) - mu * mu + 1e-5f);
  float4v g0 = *(const float4v*)(gw + lane * 8);
  float4v g1 = *(const float4v*)(gw + lane * 8 + 4);
  float4v g2 = *(const float4v*)(gw + 512 + lane * 4);
  float4v b0 = *(const float4v*)(bw + lane * 8);
  float4v b1 = *(const float4v*)(bw + lane * 8 + 4);
  float4v b2 = *(const float4v*)(bw + 512 + lane * 4);
  float o[12];
#pragma unroll
  for (int j = 0; j < 4; ++j) o[j] = (f[j] - mu) * rs * g0[j] + b0[j];
#pragma unroll
  for (int j = 0; j < 4; ++j) o[4 + j] = (f[4 + j] - mu) * rs * g1[j] + b1[j];
#pragma unroll
  for (int j = 0; j < 4; ++j) o[8 + j] = (f[8 + j] - mu) * rs * g2[j] + b2[j];
  if constexpr (OUT_F32) {
    float* orow = of + (size_t)row * D_MODEL;
    float4v t0, t1, t2;
#pragma unroll
    for (int j = 0; j < 4; ++j) { t0[j] = o[j]; t1[j] = o[4 + j]; t2[j] = o[8 + j]; }
    *(float4v*)(orow + lane * 8) = t0;
    *(float4v*)(orow + lane * 8 + 4) = t1;
    *(float4v*)(orow + 512 + lane * 4) = t2;
  } else {
    short* orow = ob + (size_t)row * D_MODEL;
    ushort4v t0, t1, t2;
#pragma unroll
    for (int j = 0; j < 4; ++j) {
      t0[j] = (unsigned short)f2bf(o[j]);
      t1[j] = (unsigned short)f2bf(o[4 + j]);
      t2[j] = (unsigned short)f2bf(o[8 + j]);
    }
    *(ushort4v*)(orow + lane * 8) = t0;
    *(ushort4v*)(orow + lane * 8 + 4) = t1;
    *(ushort4v*)(orow + 512 + lane * 4) = t2;
  }
}

// ---------------- launch ----------------
extern "C" void kernel_launch(void* const* d_in, const int* in_sizes, int n_in,
                              void* d_out, int out_size, void* d_ws, size_t ws_size,
                              hipStream_t stream) {
  const float* emb = (const float*)d_in[0];
  const int* mask = (const int*)d_in[1];
  const float* Wq = (const float*)d_in[2];
  const float* bq = (const float*)d_in[3];
  const float* Wk = (const float*)d_in[4];
  const float* bk = (const float*)d_in[5];
  const float* Wv = (const float*)d_in[6];
  const float* bv = (const float*)d_in[7];
  const float* Wo = (const float*)d_in[8];
  const float* bo = (const float*)d_in[9];
  const float* W1 = (const float*)d_in[10];
  const float* b1 = (const float*)d_in[11];
  const float* W2 = (const float*)d_in[12];
  const float* b2 = (const float*)d_in[13];
  const float* lng = (const float*)d_in[14];
  const float* lnb = (const float*)d_in[15];

  char* ws = (char*)d_ws;
  size_t off = 0;
  auto alloc = [&](size_t bytes) -> char* {
    char* p = ws + off;
    off = (off + bytes + 255) & ~(size_t)255;
    return p;
  };
  const size_t DD = (size_t)D_MODEL * D_MODEL;
  const size_t DF = (size_t)D_MODEL * FF_DIM;
  const size_t TD = (size_t)NTOK * D_MODEL;
  const size_t TF = (size_t)NTOK * FF_DIM;

  short* wqkvt = (short*)alloc(3 * DD * 2);
  short* wot = (short*)alloc(DD * 2);
  short* w1t = (short*)alloc(DF * 2);
  short* w2t = (short*)alloc(DF * 2);
  float* bqkv = (float*)alloc(2304 * 4);
  short* x0 = (short*)alloc(TD * 2);     // emb bf16; reused as ctx after QKV
  short* qkv = (short*)alloc(3 * TD * 2);
  short* aresb = (short*)alloc(TD * 2);
  short* xbf = (short*)alloc(TD * 2);
  short* hbf = (short*)alloc(TF * 2);    // FF hidden; ALSO aliased as opart before FF
  short* ffresb = (short*)alloc(TD * 2);
  float* lpart = (float*)alloc(2 * (size_t)BATCH * NHEADS * SEQ * 4);
  short* qb = qkv;
  short* kb = qkv + TD;
  short* vtb = qkv + 2 * TD;
  short* ctx = x0;
  float* opart = (float*)hbf;  // 50.3MB == TF*2 bytes; dead before FF1

  prep<<<dim3(1729 + (int)(TD / 1024)), 256, 0, stream>>>(
      Wq, Wk, Wv, Wo, W1, W2, bq, bk, bv, emb, wqkvt, wot, w1t, w2t, bqkv, x0);
  gemm_bt<EPI_QKV><<<dim3(18, 64), 256, 0, stream>>>(
      x0, wqkvt, bqkv, nullptr, nullptr, qkv, NTOK, 3 * D_MODEL, D_MODEL);
  attn_fa6<<<dim3(768), 256, 0, stream>>>(qb, kb, vtb, mask, opart, lpart);
  attn_combine<<<dim3((int)((size_t)BATCH * NHEADS * SEQ * 64 / 4 / 256)), 256, 0, stream>>>(
      opart, lpart, ctx);
  gemm_bn64<EPI_WO><<<dim3(12, 64), 256, 0, stream>>>(
      ctx, wot, bo, emb, nullptr, aresb, NTOK, D_MODEL, D_MODEL);
  ln_w<0><<<dim3(NTOK / 4), 256, 0, stream>>>(aresb, lng, lnb, nullptr, xbf);
  gemm_bt<EPI_RELU><<<dim3(24, 64), 256, 0, stream>>>(
      xbf, w1t, b1, nullptr, nullptr, hbf, NTOK, FF_DIM, D_MODEL);
  gemm_bn64<EPI_FF><<<dim3(12, 64), 256, 0, stream>>>(
      hbf, w2t, b2, nullptr, xbf, ffresb, NTOK, D_MODEL, FF_DIM);
  ln_w<1><<<dim3(NTOK / 4), 256, 0, stream>>>(ffresb, lng, lnb, (float*)d_out, nullptr);
}

// Round 10
// 284.552 us; speedup vs baseline: 1.0983x; 1.0167x over previous
//
#include <hip/hip_runtime.h>

#define D_MODEL 768
#define NHEADS  12
#define SEQ     2048
#define BATCH   4
#define FF_DIM  3072
#define NTOK    (BATCH * SEQ)

typedef short short8 __attribute__((ext_vector_type(8)));
typedef float f32x4 __attribute__((ext_vector_type(4)));
typedef float f32x16 __attribute__((ext_vector_type(16)));
typedef int int4v __attribute__((ext_vector_type(4)));
typedef int int2v __attribute__((ext_vector_type(2)));
typedef unsigned short ushort4v __attribute__((ext_vector_type(4)));
typedef float float4v __attribute__((ext_vector_type(4)));

__device__ __forceinline__ short f2bf(float x) {
  unsigned u = __builtin_bit_cast(unsigned, x);
  u += 0x7fffu + ((u >> 16) & 1u);   // RNE
  return (short)(u >> 16);
}
__device__ __forceinline__ float bf2f(short x) {
  return __builtin_bit_cast(float, ((unsigned)(unsigned short)x) << 16);
}
__device__ __forceinline__ int cvtpk(float a, float b) {
  int r;
  asm("v_cvt_pk_bf16_f32 %0, %1, %2" : "=v"(r) : "v"(a), "v"(b));
  return r;  // lo16 = bf16(a), hi16 = bf16(b)
}
__device__ __forceinline__ float fexp2(float x) {
#if __has_builtin(__builtin_amdgcn_exp2f)
  return __builtin_amdgcn_exp2f(x);   // single v_exp_f32
#else
  return exp2f(x);
#endif
}
__device__ __forceinline__ float frcp(float x) {
#if __has_builtin(__builtin_amdgcn_rcpf)
  return __builtin_amdgcn_rcpf(x);    // single v_rcp_f32
#else
  return 1.f / x;
#endif
}
__device__ __forceinline__ void gll16(const void* g, void* l) {
  __builtin_amdgcn_global_load_lds(
      (const __attribute__((address_space(1))) void*)g,
      (__attribute__((address_space(3))) void*)l, 16, 0, 0);
}

// ---------------- prep: all weight transposes + bias concat + emb cast ----------------
__device__ __forceinline__ void wt_tile(float (*T)[65], const float* __restrict__ W,
                                        short* __restrict__ Wt, int K, int N,
                                        int bx, int by, int t) {
  const int c = t & 63, rb = t >> 6;
  const int k0 = by * 64, n0 = bx * 64;
#pragma unroll
  for (int i = 0; i < 16; ++i) {
    const int r = rb * 16 + i;
    T[c][r] = W[(size_t)(k0 + r) * N + n0 + c];
  }
  __syncthreads();
#pragma unroll
  for (int j = 0; j < 16; ++j) {
    const int idx = t + j * 256;
    const int nl = idx >> 6, kl = idx & 63;
    Wt[(size_t)(n0 + nl) * K + k0 + kl] = f2bf(T[nl][kl]);
  }
}

__global__ __launch_bounds__(256) void prep(
    const float* __restrict__ Wq, const float* __restrict__ Wk, const float* __restrict__ Wv,
    const float* __restrict__ Wo, const float* __restrict__ W1, const float* __restrict__ W2,
    const float* __restrict__ bq, const float* __restrict__ bk, const float* __restrict__ bv,
    const float* __restrict__ emb,
    short* __restrict__ wqkvt, short* __restrict__ wot, short* __restrict__ w1t,
    short* __restrict__ w2t, float* __restrict__ bqkv, short* __restrict__ x0) {
  __shared__ float T[64][65];
  const int bi = blockIdx.x;
  const int t = threadIdx.x;
  if (bi < 432) {
    const int s = bi / 144, l = bi % 144;
    const float* W = (s == 0) ? Wq : (s == 1) ? Wk : Wv;
    wt_tile(T, W, wqkvt + (size_t)s * 768 * 768, 768, 768, l % 12, l / 12, t);
  } else if (bi < 576) {
    const int l = bi - 432;
    wt_tile(T, Wo, wot, 768, 768, l % 12, l / 12, t);
  } else if (bi < 1152) {
    const int l = bi - 576;
    wt_tile(T, W1, w1t, 768, 3072, l % 48, l / 48, t);
  } else if (bi < 1728) {
    const int l = bi - 1152;
    wt_tile(T, W2, w2t, 3072, 768, l % 12, l / 12, t);
  } else if (bi == 1728) {
#pragma unroll
    for (int j = 0; j < 9; ++j) {
      const int i = t + j * 256;
      bqkv[i] = (i < 768) ? bq[i] : (i < 1536) ? bk[i - 768] : bv[i - 1536];
    }
  } else {
    const int i = (bi - 1729) * 256 + t;
    float4v v = *(const float4v*)(emb + (size_t)i * 4);
    ushort4v p;
    p[0] = (unsigned short)f2bf(v[0]);
    p[1] = (unsigned short)f2bf(v[1]);
    p[2] = (unsigned short)f2bf(v[2]);
    p[3] = (unsigned short)f2bf(v[3]);
    *(ushort4v*)(x0 + (size_t)i * 4) = p;
  }
}

// ---------------- GEMM 128x128: C = A x Bt^T, fused epilogues ----------------
enum { EPI_QKV = 0, EPI_WO = 1, EPI_RELU = 2, EPI_FF = 3 };

template <int EPI>
__global__ __launch_bounds__(256) void gemm_bt(const short* __restrict__ A,
                                               const short* __restrict__ Bt,
                                               const float* __restrict__ bias,
                                               const float* __restrict__ extraF,
                                               const short* __restrict__ extraB,
                                               void* __restrict__ outp,
                                               int M, int N, int K) {
  __shared__ short As[128 * 64];
  __shared__ short Bs[128 * 64];
  const int tid = threadIdx.x;
  const int lane = tid & 63, wid = tid >> 6;
  const int wr = wid >> 1, wc = wid & 1;
  const int l16 = lane & 15, lg = lane >> 4;
  const int brow = blockIdx.y * 128, bcol = blockIdx.x * 128;

  f32x4 acc[4][4];
#pragma unroll
  for (int i = 0; i < 4; ++i)
#pragma unroll
    for (int j = 0; j < 4; ++j) acc[i][j] = (f32x4){0.f, 0.f, 0.f, 0.f};

  for (int kt = 0; kt < K; kt += 64) {
    __syncthreads();
#pragma unroll
    for (int i = 0; i < 4; ++i) {
      const int c = wid * 256 + i * 64 + lane;
      const int row = c >> 3;
      const int gc = (c & 7) ^ (row & 7);           // pre-swizzled global source
      gll16(A + (size_t)(brow + row) * K + kt + gc * 8,
            (char*)As + (wid * 256 + i * 64) * 16);
      gll16(Bt + (size_t)(bcol + row) * K + kt + gc * 8,
            (char*)Bs + (wid * 256 + i * 64) * 16);
    }
    __syncthreads();
#pragma unroll
    for (int kc = 0; kc < 2; ++kc) {
      short8 af[4], bfr[4];
#pragma unroll
      for (int m = 0; m < 4; ++m) {
        const int row = wr * 64 + m * 16 + l16;
        const int ch = (kc * 4 + lg) ^ (row & 7);
        af[m] = *(const short8*)((const char*)As + row * 128 + ch * 16);
      }
#pragma unroll
      for (int n = 0; n < 4; ++n) {
        const int row = wc * 64 + n * 16 + l16;
        const int ch = (kc * 4 + lg) ^ (row & 7);
        bfr[n] = *(const short8*)((const char*)Bs + row * 128 + ch * 16);
      }
#pragma unroll
      for (int m = 0; m < 4; ++m)
#pragma unroll
        for (int n = 0; n < 4; ++n)
          acc[m][n] = __builtin_amdgcn_mfma_f32_16x16x32_bf16(af[m], bfr[n],
                                                              acc[m][n], 0, 0, 0);
    }
  }

  const int mbase = brow + wr * 64;
  const int nbase = bcol + wc * 64;

  if constexpr (EPI == EPI_QKV) {
    short* qb_ = (short*)outp;
    short* kb_ = qb_ + (size_t)NTOK * D_MODEL;
    short* vt_ = kb_ + (size_t)NTOK * D_MODEL;
    const int type = nbase / 768;  // block-uniform
#pragma unroll
    for (int ni = 0; ni < 4; ++ni) {
      const int n = nbase + ni * 16 + l16;
      const float bv = bias[n];
      const int ncol = n - type * 768;
      const int h = ncol >> 6, dk = ncol & 63;
      if (type == 2) {  // V: transposed store [bh][dk][s]
#pragma unroll
        for (int mi = 0; mi < 4; ++mi) {
          const int m0 = mbase + mi * 16 + lg * 4;
          const int bidx = m0 >> 11, s0 = m0 & 2047;
          ushort4v pk;
#pragma unroll
          for (int r = 0; r < 4; ++r) pk[r] = (unsigned short)f2bf(acc[mi][ni][r] + bv);
          *(ushort4v*)(vt_ + (((size_t)bidx * NHEADS + h) * 64 + dk) * SEQ + s0) = pk;
        }
      } else {
        short* o = (type == 0) ? qb_ : kb_;
        const float sc = (type == 0) ? 0.125f * 1.44269504f : 1.f;  // Q: 1/sqrt(DK)*log2e
#pragma unroll
        for (int mi = 0; mi < 4; ++mi) {
#pragma unroll
          for (int r = 0; r < 4; ++r) {
            const int m = mbase + mi * 16 + lg * 4 + r;
            const int bidx = m >> 11, sidx = m & 2047;
            o[(((size_t)bidx * NHEADS + h) * SEQ + sidx) * 64 + dk] =
                f2bf((acc[mi][ni][r] + bv) * sc);
          }
        }
      }
    }
  } else {  // EPI_RELU -> bf16 (only other 128x128 user)
    short* o = (short*)outp;
#pragma unroll
    for (int ni = 0; ni < 4; ++ni) {
      const int n = nbase + ni * 16 + l16;
      const float bv = bias[n];
#pragma unroll
      for (int mi = 0; mi < 4; ++mi)
#pragma unroll
        for (int r = 0; r < 4; ++r) {
          const int m = mbase + mi * 16 + lg * 4 + r;
          o[(size_t)m * N + n] = f2bf(fmaxf(acc[mi][ni][r] + bv, 0.f));
        }
    }
  }
}

// ---------------- GEMM 128x64 (BN=64): for N=768 GEMMs (WO, FF2) ----------------
template <int EPI>
__global__ __launch_bounds__(256) void gemm_bn64(const short* __restrict__ A,
                                                 const short* __restrict__ Bt,
                                                 const float* __restrict__ bias,
                                                 const float* __restrict__ extraF,
                                                 const short* __restrict__ extraB,
                                                 void* __restrict__ outp,
                                                 int M, int N, int K) {
  __shared__ short As[128 * 64];
  __shared__ short Bs[64 * 64];
  const int tid = threadIdx.x;
  const int lane = tid & 63, wid = tid >> 6;
  const int l16 = lane & 15, lg = lane >> 4;
  const int brow = blockIdx.y * 128, bcol = blockIdx.x * 64;

  f32x4 acc[2][4];
#pragma unroll
  for (int i = 0; i < 2; ++i)
#pragma unroll
    for (int j = 0; j < 4; ++j) acc[i][j] = (f32x4){0.f, 0.f, 0.f, 0.f};

  for (int kt = 0; kt < K; kt += 64) {
    __syncthreads();
#pragma unroll
    for (int i = 0; i < 4; ++i) {  // A: 4 chunks/thread
      const int c = wid * 256 + i * 64 + lane;
      const int row = c >> 3;
      const int gc = (c & 7) ^ (row & 7);
      gll16(A + (size_t)(brow + row) * K + kt + gc * 8,
            (char*)As + (wid * 256 + i * 64) * 16);
    }
#pragma unroll
    for (int i = 0; i < 2; ++i) {  // B: 2 chunks/thread
      const int c = i * 256 + tid;
      const int row = c >> 3;
      const int gc = (c & 7) ^ (row & 7);
      gll16(Bt + (size_t)(bcol + row) * K + kt + gc * 8,
            (char*)Bs + (i * 256 + wid * 64) * 16);
    }
    __syncthreads();
#pragma unroll
    for (int kc = 0; kc < 2; ++kc) {
      short8 af[2], bfr[4];
#pragma unroll
      for (int m = 0; m < 2; ++m) {
        const int row = wid * 32 + m * 16 + l16;
        const int ch = (kc * 4 + lg) ^ (row & 7);
        af[m] = *(const short8*)((const char*)As + row * 128 + ch * 16);
      }
#pragma unroll
      for (int n = 0; n < 4; ++n) {
        const int row = n * 16 + l16;
        const int ch = (kc * 4 + lg) ^ (row & 7);
        bfr[n] = *(const short8*)((const char*)Bs + row * 128 + ch * 16);
      }
#pragma unroll
      for (int m = 0; m < 2; ++m)
#pragma unroll
        for (int n = 0; n < 4; ++n)
          acc[m][n] = __builtin_amdgcn_mfma_f32_16x16x32_bf16(af[m], bfr[n],
                                                              acc[m][n], 0, 0, 0);
    }
  }

  const int mbase = brow + wid * 32;
#pragma unroll
  for (int ni = 0; ni < 4; ++ni) {
    const int n = bcol + ni * 16 + l16;
    const float bv = bias[n];
#pragma unroll
    for (int mi = 0; mi < 2; ++mi)
#pragma unroll
      for (int r = 0; r < 4; ++r) {
        const int m = mbase + mi * 16 + lg * 4 + r;
        const size_t idx = (size_t)m * N + n;
        if constexpr (EPI == EPI_WO) {
          ((short*)outp)[idx] = f2bf(acc[mi][ni][r] + bv + extraF[idx]);
        } else {  // EPI_FF
          ((short*)outp)[idx] = f2bf(acc[mi][ni][r] + bv + bf2f(extraB[idx]));
        }
      }
  }
}

// ---------------- flash attention: + kZero C-operand, bf16 partials ----------------
__global__ __launch_bounds__(256) void attn_fa6(
    const short* __restrict__ Q,   // [BH,S,64] pre-scaled by 0.125*log2e
    const short* __restrict__ Kb,  // [BH,S,64]
    const short* __restrict__ Vt,  // [BH,64,S]
    const int* __restrict__ mask,  // [B,S]
    short* __restrict__ opart,     // [2][BH][S][64] unnormalized bf16
    float* __restrict__ lpart) {   // [2][BH][S]
  __shared__ short KsA[64 * 64], KsB[64 * 64];
  __shared__ short VsA[64 * 64], VsB[64 * 64];
  const int tid = threadIdx.x;
  const int lane = tid & 63, w = tid >> 6;
  const int l31 = lane & 31, hi = lane >> 5;

  // XCD-chunked remap: all 8 q-blocks of one (bh,half) on one XCD
  const int i = blockIdx.x;               // [0,768)
  const int r8 = i & 7, qq = i >> 3;
  const int bhz = ((qq >> 3) << 3) + r8;  // [0,96)
  const int qblk = qq & 7;
  const int half = bhz / 48, bh = bhz % 48;
  const int b = bh / NHEADS;
  const int q0 = qblk * 256 + w * 64;
  const int kvbase = half * (SEQ / 2);

  const short* qpA = Q + ((size_t)bh * SEQ + q0 + l31) * 64;
  const short* qpB = qpA + 32 * 64;
  short8 qfA[4], qfB[4];
#pragma unroll
  for (int s = 0; s < 4; ++s) {
    qfA[s] = *(const short8*)(qpA + s * 16 + hi * 8);
    qfB[s] = *(const short8*)(qpB + s * 16 + hi * 8);
  }

  f32x16 kZero;   // persistent zeros: C-operand for QK^T slot 0 (kills 128 movs/tile)
#pragma unroll
  for (int k = 0; k < 16; ++k) kZero[k] = 0.f;

  f32x16 o0a, o1a, o0b, o1b;
#pragma unroll
  for (int k = 0; k < 16; ++k) { o0a[k] = 0.f; o1a[k] = 0.f; o0b[k] = 0.f; o1b[k] = 0.f; }
  float lA = 0.f, lB = 0.f;  // per-lane; cross-half reduce deferred to epilogue

  auto stage = [&](short* Ksd, short* Vsd, int kv0) {
#pragma unroll
    for (int i2 = 0; i2 < 2; ++i2) {
      const int c = i2 * 256 + tid;
      const int row = c >> 3;
      const int gc = (c & 7) ^ (row & 7);  // pre-swizzled source, linear LDS dest
      gll16(Kb + ((size_t)bh * SEQ + kv0 + row) * 64 + gc * 8,
            (char*)Ksd + (i2 * 256 + w * 64) * 16);
      gll16(Vt + ((size_t)bh * 64 + row) * SEQ + kv0 + gc * 8,
            (char*)Vsd + (i2 * 256 + w * 64) * 16);
    }
  };

  stage(KsA, VsA, kvbase);
  __syncthreads();

  for (int t = 0; t < SEQ / 2 / 64; ++t) {
    const short* Ksc = (t & 1) ? KsB : KsA;
    const short* Vsc = (t & 1) ? VsB : VsA;

    const int mv = mask[(size_t)b * SEQ + kvbase + t * 64 + lane];
    const bool anym = __any(mv == 0);
    short8 paA[4], paB[4];

#pragma unroll
    for (int ph = 0; ph < 2; ++ph) {
      f32x16 sa, sb;
      const char* kr = (const char*)Ksc + (ph * 32 + l31) * 128;
      __builtin_amdgcn_s_setprio(1);
      {  // slot 0: C = kZero (no per-tile accumulator zero-init)
        const int ch = hi ^ (l31 & 7);
        short8 kf = *(const short8*)(kr + ch * 16);
        sa = __builtin_amdgcn_mfma_f32_32x32x16_bf16(kf, qfA[0], kZero, 0, 0, 0);
        sb = __builtin_amdgcn_mfma_f32_32x32x16_bf16(kf, qfB[0], kZero, 0, 0, 0);
      }
#pragma unroll
      for (int slot = 1; slot < 4; ++slot) {
        const int ch = (slot * 2 + hi) ^ (l31 & 7);
        short8 kf = *(const short8*)(kr + ch * 16);
        sa = __builtin_amdgcn_mfma_f32_32x32x16_bf16(kf, qfA[slot], sa, 0, 0, 0);
        sb = __builtin_amdgcn_mfma_f32_32x32x16_bf16(kf, qfB[slot], sb, 0, 0, 0);
      }
      __builtin_amdgcn_s_setprio(0);
      if (ph == 1 && t + 1 < SEQ / 2 / 64)  // stage next tile; lands during sm+PV
        stage((t & 1) ? KsA : KsB, (t & 1) ? VsA : VsB, kvbase + (t + 1) * 64);
      if (anym) {
#pragma unroll
        for (int r = 0; r < 16; ++r) {
          const int cr = ph * 32 + (r & 3) + 8 * (r >> 2) + 4 * hi;
          if (__shfl(mv, cr) == 0) { sa[r] = -1e9f; sb[r] = -1e9f; }
        }
      }
#pragma unroll
      for (int r = 0; r < 16; ++r) {
        sa[r] = fexp2(sa[r]);
        sb[r] = fexp2(sb[r]);
        lA += sa[r];
        lB += sb[r];
      }
      // pack P -> bf16 A-frags (cvt_pk + lane^32 swap)
#pragma unroll
      for (int ks = 0; ks < 2; ++ks) {
        const int rb0 = ks * 8;
#pragma unroll
        for (int g = 0; g < 2; ++g) {
          const f32x16& sc = g ? sb : sa;
          int x0_ = cvtpk(sc[rb0 + 0], sc[rb0 + 1]);
          int y0_ = cvtpk(sc[rb0 + 4], sc[rb0 + 5]);
          int x1_ = cvtpk(sc[rb0 + 2], sc[rb0 + 3]);
          int y1_ = cvtpk(sc[rb0 + 6], sc[rb0 + 7]);
          int4v pw;
#if __has_builtin(__builtin_amdgcn_permlane32_swap)
          int2v r0 = __builtin_amdgcn_permlane32_swap(x0_, y0_, false, false);
          int2v r1 = __builtin_amdgcn_permlane32_swap(x1_, y1_, false, false);
          pw[0] = r0[0]; pw[1] = r1[0]; pw[2] = r0[1]; pw[3] = r1[1];
#else
          const int ys0 = __shfl_xor(y0_, 32);
          const int xs0 = __shfl_xor(x0_, 32);
          const int ys1 = __shfl_xor(y1_, 32);
          const int xs1 = __shfl_xor(x1_, 32);
          pw[0] = hi ? ys0 : x0_;
          pw[1] = hi ? ys1 : x1_;
          pw[2] = hi ? y0_ : xs0;
          pw[3] = hi ? y1_ : xs1;
#endif
          const short8 pa = __builtin_bit_cast(short8, pw);
          if (g) paB[ph * 2 + ks] = pa; else paA[ph * 2 + ks] = pa;
        }
      }
    }

    // ---- PV from LDS: every V-fragment read feeds both q-groups ----
    __builtin_amdgcn_s_setprio(1);
#pragma unroll
    for (int vs = 0; vs < 4; ++vs) {
      const int vch = (vs * 2 + hi) ^ (l31 & 7);
      short8 vb0 = *(const short8*)((const char*)Vsc + l31 * 128 + vch * 16);
      short8 vb1 = *(const short8*)((const char*)Vsc + (32 + l31) * 128 + vch * 16);
      o0a = __builtin_amdgcn_mfma_f32_32x32x16_bf16(paA[vs], vb0, o0a, 0, 0, 0);
      o0b = __builtin_amdgcn_mfma_f32_32x32x16_bf16(paB[vs], vb0, o0b, 0, 0, 0);
      o1a = __builtin_amdgcn_mfma_f32_32x32x16_bf16(paA[vs], vb1, o1a, 0, 0, 0);
      o1b = __builtin_amdgcn_mfma_f32_32x32x16_bf16(paB[vs], vb1, o1b, 0, 0, 0);
    }
    __builtin_amdgcn_s_setprio(0);
    __syncthreads();
  }

  lA += __shfl_xor(lA, 32);
  lB += __shfl_xor(lB, 32);

  // ---- epilogue: unnormalized bf16 partials ----
  short* opA = opart + ((size_t)half * BATCH * NHEADS + bh) * SEQ * 64;
#pragma unroll
  for (int r = 0; r < 16; ++r) {
    const int q = (r & 3) + 8 * (r >> 2) + 4 * hi;
    short* pa_ = opA + (size_t)(q0 + q) * 64;
    pa_[l31] = f2bf(o0a[r]);
    pa_[32 + l31] = f2bf(o1a[r]);
    short* pb_ = opA + (size_t)(q0 + 32 + q) * 64;
    pb_[l31] = f2bf(o0b[r]);
    pb_[32 + l31] = f2bf(o1b[r]);
  }
  if (lane < 32) {
    float* lp = lpart + (size_t)half * BATCH * NHEADS * SEQ + (size_t)bh * SEQ + q0;
    lp[l31] = lA;
    lp[32 + l31] = lB;
  }
}

// ---------------- combine: ctx = (O0+O1)/(l0+l1), bf16 in/out, 8 elems/thread ----
__global__ __launch_bounds__(256) void attn_combine(const short* __restrict__ op,
                                                    const float* __restrict__ lp,
                                                    short* __restrict__ ctx) {
  const size_t HS = (size_t)BATCH * NHEADS * SEQ * 64;  // elems per half
  const int i8 = blockIdx.x * 256 + threadIdx.x;        // 8-elem units
  const size_t base = (size_t)i8 * 8;
  short8 a = *(const short8*)(op + base);
  short8 c = *(const short8*)(op + HS + base);
  const int row = (int)(base >> 6);                     // bh*SEQ + q
  const float inv = frcp(lp[row] + lp[BATCH * NHEADS * SEQ + row]);
  const int bh = row >> 11, q = row & 2047;
  const int b = bh / NHEADS, h = bh - b * NHEADS;
  const int dk = (int)(base & 63);
  short8 o;
#pragma unroll
  for (int j = 0; j < 8; ++j) o[j] = f2bf((bf2f(a[j]) + bf2f(c[j])) * inv);
  *(short8*)(ctx + ((size_t)b * SEQ + q) * D_MODEL + h * 64 + dk) = o;
}

// ---------------- LayerNorm: one wave per row, bf16 in, bf16/f32 out ----------------
template <int OUT_F32>
__global__ __launch_bounds__(256) void ln_w(const short* __restrict__ y,
                                            const float* __restrict__ gw,
                                            const float* __restrict__ bw,
                                            float* __restrict__ of,
                                            short* __restrict__ ob) {
  const int lane = threadIdx.x & 63, w = threadIdx.x >> 6;
  const int row = blockIdx.x * 4 + w;
  const short* yr = y + (size_t)row * D_MODEL;
  short8 v8 = *(const short8*)(yr + lane * 8);
  ushort4v v4 = *(const ushort4v*)(yr + 512 + lane * 4);
  float f[12];
#pragma unroll
  for (int j = 0; j < 8; ++j) f[j] = bf2f(v8[j]);
#pragma unroll
  for (int j = 0; j < 4; ++j) f[8 + j] = bf2f((short)v4[j]);
  float s = 0.f, q = 0.f;
#pragma unroll
  for (int j = 0; j < 12; ++j) { s += f[j]; q += f[j] * f[j]; }
#pragma unroll
  for (int mm = 1; mm < 64; mm <<= 1) {
    s += __shfl_xor(s, mm);
    q += __shfl_xor(q, mm);
  }
  const float mu = s * (1.f / D_MODEL);
  const float rs = rsqrtf(q * (1.f / D_MODEL) - mu * mu + 1e-5f);
  float4v g0 = *(const float4v*)(gw + lane * 8);
  float4v g1 = *(const float4v*)(gw + lane * 8 + 4);
  float4v g2 = *(const float4v*)(gw + 512 + lane * 4);
  float4v b0 = *(const float4v*)(bw + lane * 8);
  float4v b1 = *(const float4v*)(bw + lane * 8 + 4);
  float4v b2 = *(const float4v*)(bw + 512 + lane * 4);
  float o[12];
#pragma unroll
  for (int j = 0; j < 4; ++j) o[j] = (f[j] - mu) * rs * g0[j] + b0[j];
#pragma unroll
  for (int j = 0; j < 4; ++j) o[4 + j] = (f[4 + j] - mu) * rs * g1[j] + b1[j];
#pragma unroll
  for (int j = 0; j < 4; ++j) o[8 + j] = (f[8 + j] - mu) * rs * g2[j] + b2[j];
  if constexpr (OUT_F32) {
    float* orow = of + (size_t)row * D_MODEL;
    float4v t0, t1, t2;
#pragma unroll
    for (int j = 0; j < 4; ++j) { t0[j] = o[j]; t1[j] = o[4 + j]; t2[j] = o[8 + j]; }
    *(float4v*)(orow + lane * 8) = t0;
    *(float4v*)(orow + lane * 8 + 4) = t1;
    *(float4v*)(orow + 512 + lane * 4) = t2;
  } else {
    short* orow = ob + (size_t)row * D_MODEL;
    ushort4v t0, t1, t2;
#pragma unroll
    for (int j = 0; j < 4; ++j) {
      t0[j] = (unsigned short)f2bf(o[j]);
      t1[j] = (unsigned short)f2bf(o[4 + j]);
      t2[j] = (unsigned short)f2bf(o[8 + j]);
    }
    *(ushort4v*)(orow + lane * 8) = t0;
    *(ushort4v*)(orow + lane * 8 + 4) = t1;
    *(ushort4v*)(orow + 512 + lane * 4) = t2;
  }
}

// ---------------- launch ----------------
extern "C" void kernel_launch(void* const* d_in, const int* in_sizes, int n_in,
                              void* d_out, int out_size, void* d_ws, size_t ws_size,
                              hipStream_t stream) {
  const float* emb = (const float*)d_in[0];
  const int* mask = (const int*)d_in[1];
  const float* Wq = (const float*)d_in[2];
  const float* bq = (const float*)d_in[3];
  const float* Wk = (const float*)d_in[4];
  const float* bk = (const float*)d_in[5];
  const float* Wv = (const float*)d_in[6];
  const float* bv = (const float*)d_in[7];
  const float* Wo = (const float*)d_in[8];
  const float* bo = (const float*)d_in[9];
  const float* W1 = (const float*)d_in[10];
  const float* b1 = (const float*)d_in[11];
  const float* W2 = (const float*)d_in[12];
  const float* b2 = (const float*)d_in[13];
  const float* lng = (const float*)d_in[14];
  const float* lnb = (const float*)d_in[15];

  char* ws = (char*)d_ws;
  size_t off = 0;
  auto alloc = [&](size_t bytes) -> char* {
    char* p = ws + off;
    off = (off + bytes + 255) & ~(size_t)255;
    return p;
  };
  const size_t DD = (size_t)D_MODEL * D_MODEL;
  const size_t DF = (size_t)D_MODEL * FF_DIM;
  const size_t TD = (size_t)NTOK * D_MODEL;
  const size_t TF = (size_t)NTOK * FF_DIM;

  short* wqkvt = (short*)alloc(3 * DD * 2);
  short* wot = (short*)alloc(DD * 2);
  short* w1t = (short*)alloc(DF * 2);
  short* w2t = (short*)alloc(DF * 2);
  float* bqkv = (float*)alloc(2304 * 4);
  short* x0 = (short*)alloc(TD * 2);     // emb bf16; reused as ctx after QKV
  short* qkv = (short*)alloc(3 * TD * 2);
  short* aresb = (short*)alloc(TD * 2);
  short* xbf = (short*)alloc(TD * 2);
  short* hbf = (short*)alloc(TF * 2);    // FF hidden; ALSO aliased as opart before FF
  short* ffresb = (short*)alloc(TD * 2);
  float* lpart = (float*)alloc(2 * (size_t)BATCH * NHEADS * SEQ * 4);
  short* qb = qkv;
  short* kb = qkv + TD;
  short* vtb = qkv + 2 * TD;
  short* ctx = x0;
  short* opart = hbf;  // 2*BH*S*64*2B = 25.2MB <= TF*2 bytes; dead before FF1

  prep<<<dim3(1729 + (int)(TD / 1024)), 256, 0, stream>>>(
      Wq, Wk, Wv, Wo, W1, W2, bq, bk, bv, emb, wqkvt, wot, w1t, w2t, bqkv, x0);
  gemm_bt<EPI_QKV><<<dim3(18, 64), 256, 0, stream>>>(
      x0, wqkvt, bqkv, nullptr, nullptr, qkv, NTOK, 3 * D_MODEL, D_MODEL);
  attn_fa6<<<dim3(768), 256, 0, stream>>>(qb, kb, vtb, mask, opart, lpart);
  attn_combine<<<dim3((int)((size_t)BATCH * NHEADS * SEQ * 64 / 8 / 256)), 256, 0, stream>>>(
      opart, lpart, ctx);
  gemm_bn64<EPI_WO><<<dim3(12, 64), 256, 0, stream>>>(
      ctx, wot, bo, emb, nullptr, aresb, NTOK, D_MODEL, D_MODEL);
  ln_w<0><<<dim3(NTOK / 4), 256, 0, stream>>>(aresb, lng, lnb, nullptr, xbf);
  gemm_bt<EPI_RELU><<<dim3(24, 64), 256, 0, stream>>>(
      xbf, w1t, b1, nullptr, nullptr, hbf, NTOK, FF_DIM, D_MODEL);
  gemm_bn64<EPI_FF><<<dim3(12, 64), 256, 0, stream>>>(
      hbf, w2t, b2, nullptr, xbf, ffresb, NTOK, D_MODEL, FF_DIM);
  ln_w<1><<<dim3(NTOK / 4), 256, 0, stream>>>(ffresb, lng, lnb, (float*)d_out, nullptr);
}

// Round 11
// 283.600 us; speedup vs baseline: 1.1020x; 1.0034x over previous
//
#include <hip/hip_runtime.h>

#define D_MODEL 768
#define NHEADS  12
#define SEQ     2048
#define BATCH   4
#define FF_DIM  3072
#define NTOK    (BATCH * SEQ)

typedef short short8 __attribute__((ext_vector_type(8)));
typedef float f32x4 __attribute__((ext_vector_type(4)));
typedef float f32x16 __attribute__((ext_vector_type(16)));
typedef int int4v __attribute__((ext_vector_type(4)));
typedef int int2v __attribute__((ext_vector_type(2)));
typedef unsigned short ushort4v __attribute__((ext_vector_type(4)));
typedef float float4v __attribute__((ext_vector_type(4)));

__device__ __forceinline__ short f2bf(float x) {
  unsigned u = __builtin_bit_cast(unsigned, x);
  u += 0x7fffu + ((u >> 16) & 1u);   // RNE
  return (short)(u >> 16);
}
__device__ __forceinline__ float bf2f(short x) {
  return __builtin_bit_cast(float, ((unsigned)(unsigned short)x) << 16);
}
__device__ __forceinline__ int cvtpk(float a, float b) {
  int r;
  asm("v_cvt_pk_bf16_f32 %0, %1, %2" : "=v"(r) : "v"(a), "v"(b));
  return r;  // lo16 = bf16(a), hi16 = bf16(b)
}
__device__ __forceinline__ float fexp2(float x) {
#if __has_builtin(__builtin_amdgcn_exp2f)
  return __builtin_amdgcn_exp2f(x);   // single v_exp_f32
#else
  return exp2f(x);
#endif
}
__device__ __forceinline__ float frcp(float x) {
#if __has_builtin(__builtin_amdgcn_rcpf)
  return __builtin_amdgcn_rcpf(x);    // single v_rcp_f32
#else
  return 1.f / x;
#endif
}
__device__ __forceinline__ void gll16(const void* g, void* l) {
  __builtin_amdgcn_global_load_lds(
      (const __attribute__((address_space(1))) void*)g,
      (__attribute__((address_space(3))) void*)l, 16, 0, 0);
}

// ---------------- prep: all weight transposes + bias concat + emb cast ----------------
__device__ __forceinline__ void wt_tile(float (*T)[65], const float* __restrict__ W,
                                        short* __restrict__ Wt, int K, int N,
                                        int bx, int by, int t) {
  const int c = t & 63, rb = t >> 6;
  const int k0 = by * 64, n0 = bx * 64;
#pragma unroll
  for (int i = 0; i < 16; ++i) {
    const int r = rb * 16 + i;
    T[c][r] = W[(size_t)(k0 + r) * N + n0 + c];
  }
  __syncthreads();
#pragma unroll
  for (int j = 0; j < 16; ++j) {
    const int idx = t + j * 256;
    const int nl = idx >> 6, kl = idx & 63;
    Wt[(size_t)(n0 + nl) * K + k0 + kl] = f2bf(T[nl][kl]);
  }
}

__global__ __launch_bounds__(256) void prep(
    const float* __restrict__ Wq, const float* __restrict__ Wk, const float* __restrict__ Wv,
    const float* __restrict__ Wo, const float* __restrict__ W1, const float* __restrict__ W2,
    const float* __restrict__ bq, const float* __restrict__ bk, const float* __restrict__ bv,
    const float* __restrict__ emb,
    short* __restrict__ wqkvt, short* __restrict__ wot, short* __restrict__ w1t,
    short* __restrict__ w2t, float* __restrict__ bqkv, short* __restrict__ x0) {
  __shared__ float T[64][65];
  const int bi = blockIdx.x;
  const int t = threadIdx.x;
  if (bi < 432) {
    const int s = bi / 144, l = bi % 144;
    const float* W = (s == 0) ? Wq : (s == 1) ? Wk : Wv;
    wt_tile(T, W, wqkvt + (size_t)s * 768 * 768, 768, 768, l % 12, l / 12, t);
  } else if (bi < 576) {
    const int l = bi - 432;
    wt_tile(T, Wo, wot, 768, 768, l % 12, l / 12, t);
  } else if (bi < 1152) {
    const int l = bi - 576;
    wt_tile(T, W1, w1t, 768, 3072, l % 48, l / 48, t);
  } else if (bi < 1728) {
    const int l = bi - 1152;
    wt_tile(T, W2, w2t, 3072, 768, l % 12, l / 12, t);
  } else if (bi == 1728) {
#pragma unroll
    for (int j = 0; j < 9; ++j) {
      const int i = t + j * 256;
      bqkv[i] = (i < 768) ? bq[i] : (i < 1536) ? bk[i - 768] : bv[i - 1536];
    }
  } else {
    const int i = (bi - 1729) * 256 + t;
    float4v v = *(const float4v*)(emb + (size_t)i * 4);
    ushort4v p;
    p[0] = (unsigned short)f2bf(v[0]);
    p[1] = (unsigned short)f2bf(v[1]);
    p[2] = (unsigned short)f2bf(v[2]);
    p[3] = (unsigned short)f2bf(v[3]);
    *(ushort4v*)(x0 + (size_t)i * 4) = p;
  }
}

// ---------------- GEMM 128x128: C = A x Bt^T, fused epilogues ----------------
enum { EPI_QKV = 0, EPI_WO = 1, EPI_RELU = 2, EPI_FF = 3 };

template <int EPI>
__global__ __launch_bounds__(256) void gemm_bt(const short* __restrict__ A,
                                               const short* __restrict__ Bt,
                                               const float* __restrict__ bias,
                                               const float* __restrict__ extraF,
                                               const short* __restrict__ extraB,
                                               void* __restrict__ outp,
                                               int M, int N, int K) {
  __shared__ short As[128 * 64];
  __shared__ short Bs[128 * 64];
  const int tid = threadIdx.x;
  const int lane = tid & 63, wid = tid >> 6;
  const int wr = wid >> 1, wc = wid & 1;
  const int l16 = lane & 15, lg = lane >> 4;
  const int brow = blockIdx.y * 128, bcol = blockIdx.x * 128;

  f32x4 acc[4][4];
#pragma unroll
  for (int i = 0; i < 4; ++i)
#pragma unroll
    for (int j = 0; j < 4; ++j) acc[i][j] = (f32x4){0.f, 0.f, 0.f, 0.f};

  for (int kt = 0; kt < K; kt += 64) {
    __syncthreads();
#pragma unroll
    for (int i = 0; i < 4; ++i) {
      const int c = wid * 256 + i * 64 + lane;
      const int row = c >> 3;
      const int gc = (c & 7) ^ (row & 7);           // pre-swizzled global source
      gll16(A + (size_t)(brow + row) * K + kt + gc * 8,
            (char*)As + (wid * 256 + i * 64) * 16);
      gll16(Bt + (size_t)(bcol + row) * K + kt + gc * 8,
            (char*)Bs + (wid * 256 + i * 64) * 16);
    }
    __syncthreads();
#pragma unroll
    for (int kc = 0; kc < 2; ++kc) {
      short8 af[4], bfr[4];
#pragma unroll
      for (int m = 0; m < 4; ++m) {
        const int row = wr * 64 + m * 16 + l16;
        const int ch = (kc * 4 + lg) ^ (row & 7);
        af[m] = *(const short8*)((const char*)As + row * 128 + ch * 16);
      }
#pragma unroll
      for (int n = 0; n < 4; ++n) {
        const int row = wc * 64 + n * 16 + l16;
        const int ch = (kc * 4 + lg) ^ (row & 7);
        bfr[n] = *(const short8*)((const char*)Bs + row * 128 + ch * 16);
      }
#pragma unroll
      for (int m = 0; m < 4; ++m)
#pragma unroll
        for (int n = 0; n < 4; ++n)
          acc[m][n] = __builtin_amdgcn_mfma_f32_16x16x32_bf16(af[m], bfr[n],
                                                              acc[m][n], 0, 0, 0);
    }
  }

  const int mbase = brow + wr * 64;
  const int nbase = bcol + wc * 64;

  if constexpr (EPI == EPI_QKV) {
    short* qb_ = (short*)outp;
    short* kb_ = qb_ + (size_t)NTOK * D_MODEL;
    short* vt_ = kb_ + (size_t)NTOK * D_MODEL;
    const int type = nbase / 768;  // block-uniform
#pragma unroll
    for (int ni = 0; ni < 4; ++ni) {
      const int n = nbase + ni * 16 + l16;
      const float bv = bias[n];
      const int ncol = n - type * 768;
      const int h = ncol >> 6, dk = ncol & 63;
      if (type == 2) {  // V: transposed store [bh][dk][s]
#pragma unroll
        for (int mi = 0; mi < 4; ++mi) {
          const int m0 = mbase + mi * 16 + lg * 4;
          const int bidx = m0 >> 11, s0 = m0 & 2047;
          ushort4v pk;
#pragma unroll
          for (int r = 0; r < 4; ++r) pk[r] = (unsigned short)f2bf(acc[mi][ni][r] + bv);
          *(ushort4v*)(vt_ + (((size_t)bidx * NHEADS + h) * 64 + dk) * SEQ + s0) = pk;
        }
      } else {
        short* o = (type == 0) ? qb_ : kb_;
        const float sc = (type == 0) ? 0.125f * 1.44269504f : 1.f;  // Q: 1/sqrt(DK)*log2e
#pragma unroll
        for (int mi = 0; mi < 4; ++mi) {
#pragma unroll
          for (int r = 0; r < 4; ++r) {
            const int m = mbase + mi * 16 + lg * 4 + r;
            const int bidx = m >> 11, sidx = m & 2047;
            o[(((size_t)bidx * NHEADS + h) * SEQ + sidx) * 64 + dk] =
                f2bf((acc[mi][ni][r] + bv) * sc);
          }
        }
      }
    }
  } else if constexpr (EPI == EPI_WO) {
    // bf16 out = acc + bias + f32 residual
    short* o = (short*)outp;
#pragma unroll
    for (int ni = 0; ni < 4; ++ni) {
      const int n = nbase + ni * 16 + l16;
      const float bv = bias[n];
#pragma unroll
      for (int mi = 0; mi < 4; ++mi)
#pragma unroll
        for (int r = 0; r < 4; ++r) {
          const int m = mbase + mi * 16 + lg * 4 + r;
          const size_t idx = (size_t)m * N + n;
          o[idx] = f2bf(acc[mi][ni][r] + bv + extraF[idx]);
        }
    }
  } else if constexpr (EPI == EPI_FF) {
    // bf16 out = acc + bias + bf16 residual
    short* o = (short*)outp;
#pragma unroll
    for (int ni = 0; ni < 4; ++ni) {
      const int n = nbase + ni * 16 + l16;
      const float bv = bias[n];
#pragma unroll
      for (int mi = 0; mi < 4; ++mi)
#pragma unroll
        for (int r = 0; r < 4; ++r) {
          const int m = mbase + mi * 16 + lg * 4 + r;
          const size_t idx = (size_t)m * N + n;
          o[idx] = f2bf(acc[mi][ni][r] + bv + bf2f(extraB[idx]));
        }
    }
  } else {  // EPI_RELU -> bf16
    short* o = (short*)outp;
#pragma unroll
    for (int ni = 0; ni < 4; ++ni) {
      const int n = nbase + ni * 16 + l16;
      const float bv = bias[n];
#pragma unroll
      for (int mi = 0; mi < 4; ++mi)
#pragma unroll
        for (int r = 0; r < 4; ++r) {
          const int m = mbase + mi * 16 + lg * 4 + r;
          o[(size_t)m * N + n] = f2bf(fmaxf(acc[mi][ni][r] + bv, 0.f));
        }
    }
  }
}

// ---------------- flash attention: LDS + KV-split + XCD-chunked + setprio ----------
__global__ __launch_bounds__(256) void attn_fa6(
    const short* __restrict__ Q,   // [BH,S,64] pre-scaled by 0.125*log2e
    const short* __restrict__ Kb,  // [BH,S,64]
    const short* __restrict__ Vt,  // [BH,64,S]
    const int* __restrict__ mask,  // [B,S]
    short* __restrict__ opart,     // [2][BH][S][64] unnormalized bf16
    float* __restrict__ lpart) {   // [2][BH][S]
  __shared__ short KsA[64 * 64], KsB[64 * 64];
  __shared__ short VsA[64 * 64], VsB[64 * 64];
  const int tid = threadIdx.x;
  const int lane = tid & 63, w = tid >> 6;
  const int l31 = lane & 31, hi = lane >> 5;

  // XCD-chunked remap: all 8 q-blocks of one (bh,half) on one XCD
  const int i = blockIdx.x;               // [0,768)
  const int r8 = i & 7, qq = i >> 3;
  const int bhz = ((qq >> 3) << 3) + r8;  // [0,96)
  const int qblk = qq & 7;
  const int half = bhz / 48, bh = bhz % 48;
  const int b = bh / NHEADS;
  const int q0 = qblk * 256 + w * 64;
  const int kvbase = half * (SEQ / 2);

  const short* qpA = Q + ((size_t)bh * SEQ + q0 + l31) * 64;
  const short* qpB = qpA + 32 * 64;
  short8 qfA[4], qfB[4];
#pragma unroll
  for (int s = 0; s < 4; ++s) {
    qfA[s] = *(const short8*)(qpA + s * 16 + hi * 8);
    qfB[s] = *(const short8*)(qpB + s * 16 + hi * 8);
  }

  f32x16 kZero;
#pragma unroll
  for (int k = 0; k < 16; ++k) kZero[k] = 0.f;

  f32x16 o0a, o1a, o0b, o1b;
#pragma unroll
  for (int k = 0; k < 16; ++k) { o0a[k] = 0.f; o1a[k] = 0.f; o0b[k] = 0.f; o1b[k] = 0.f; }
  float lA = 0.f, lB = 0.f;  // per-lane; cross-half reduce deferred to epilogue

  auto stage = [&](short* Ksd, short* Vsd, int kv0) {
#pragma unroll
    for (int i2 = 0; i2 < 2; ++i2) {
      const int c = i2 * 256 + tid;
      const int row = c >> 3;
      const int gc = (c & 7) ^ (row & 7);  // pre-swizzled source, linear LDS dest
      gll16(Kb + ((size_t)bh * SEQ + kv0 + row) * 64 + gc * 8,
            (char*)Ksd + (i2 * 256 + w * 64) * 16);
      gll16(Vt + ((size_t)bh * 64 + row) * SEQ + kv0 + gc * 8,
            (char*)Vsd + (i2 * 256 + w * 64) * 16);
    }
  };

  stage(KsA, VsA, kvbase);
  __syncthreads();

  for (int t = 0; t < SEQ / 2 / 64; ++t) {
    const short* Ksc = (t & 1) ? KsB : KsA;
    const short* Vsc = (t & 1) ? VsB : VsA;

    const int mv = mask[(size_t)b * SEQ + kvbase + t * 64 + lane];
    const bool anym = __any(mv == 0);
    short8 paA[4], paB[4];

#pragma unroll
    for (int ph = 0; ph < 2; ++ph) {
      f32x16 sa, sb;
      const char* kr = (const char*)Ksc + (ph * 32 + l31) * 128;
      __builtin_amdgcn_s_setprio(1);
      {  // slot 0: C = kZero
        const int ch = hi ^ (l31 & 7);
        short8 kf = *(const short8*)(kr + ch * 16);
        sa = __builtin_amdgcn_mfma_f32_32x32x16_bf16(kf, qfA[0], kZero, 0, 0, 0);
        sb = __builtin_amdgcn_mfma_f32_32x32x16_bf16(kf, qfB[0], kZero, 0, 0, 0);
      }
#pragma unroll
      for (int slot = 1; slot < 4; ++slot) {
        const int ch = (slot * 2 + hi) ^ (l31 & 7);
        short8 kf = *(const short8*)(kr + ch * 16);
        sa = __builtin_amdgcn_mfma_f32_32x32x16_bf16(kf, qfA[slot], sa, 0, 0, 0);
        sb = __builtin_amdgcn_mfma_f32_32x32x16_bf16(kf, qfB[slot], sb, 0, 0, 0);
      }
      __builtin_amdgcn_s_setprio(0);
      if (ph == 1 && t + 1 < SEQ / 2 / 64)  // stage next tile; lands during sm+PV
        stage((t & 1) ? KsA : KsB, (t & 1) ? VsA : VsB, kvbase + (t + 1) * 64);
      if (anym) {
#pragma unroll
        for (int r = 0; r < 16; ++r) {
          const int cr = ph * 32 + (r & 3) + 8 * (r >> 2) + 4 * hi;
          if (__shfl(mv, cr) == 0) { sa[r] = -1e9f; sb[r] = -1e9f; }
        }
      }
#pragma unroll
      for (int r = 0; r < 16; ++r) {
        sa[r] = fexp2(sa[r]);
        sb[r] = fexp2(sb[r]);
        lA += sa[r];
        lB += sb[r];
      }
      // pack P -> bf16 A-frags (cvt_pk + lane^32 swap)
#pragma unroll
      for (int ks = 0; ks < 2; ++ks) {
        const int rb0 = ks * 8;
#pragma unroll
        for (int g = 0; g < 2; ++g) {
          const f32x16& sc = g ? sb : sa;
          int x0_ = cvtpk(sc[rb0 + 0], sc[rb0 + 1]);
          int y0_ = cvtpk(sc[rb0 + 4], sc[rb0 + 5]);
          int x1_ = cvtpk(sc[rb0 + 2], sc[rb0 + 3]);
          int y1_ = cvtpk(sc[rb0 + 6], sc[rb0 + 7]);
          int4v pw;
#if __has_builtin(__builtin_amdgcn_permlane32_swap)
          int2v r0 = __builtin_amdgcn_permlane32_swap(x0_, y0_, false, false);
          int2v r1 = __builtin_amdgcn_permlane32_swap(x1_, y1_, false, false);
          pw[0] = r0[0]; pw[1] = r1[0]; pw[2] = r0[1]; pw[3] = r1[1];
#else
          const int ys0 = __shfl_xor(y0_, 32);
          const int xs0 = __shfl_xor(x0_, 32);
          const int ys1 = __shfl_xor(y1_, 32);
          const int xs1 = __shfl_xor(x1_, 32);
          pw[0] = hi ? ys0 : x0_;
          pw[1] = hi ? ys1 : x1_;
          pw[2] = hi ? y0_ : xs0;
          pw[3] = hi ? y1_ : xs1;
#endif
          const short8 pa = __builtin_bit_cast(short8, pw);
          if (g) paB[ph * 2 + ks] = pa; else paA[ph * 2 + ks] = pa;
        }
      }
    }

    // ---- PV from LDS: every V-fragment read feeds both q-groups ----
    __builtin_amdgcn_s_setprio(1);
#pragma unroll
    for (int vs = 0; vs < 4; ++vs) {
      const int vch = (vs * 2 + hi) ^ (l31 & 7);
      short8 vb0 = *(const short8*)((const char*)Vsc + l31 * 128 + vch * 16);
      short8 vb1 = *(const short8*)((const char*)Vsc + (32 + l31) * 128 + vch * 16);
      o0a = __builtin_amdgcn_mfma_f32_32x32x16_bf16(paA[vs], vb0, o0a, 0, 0, 0);
      o0b = __builtin_amdgcn_mfma_f32_32x32x16_bf16(paB[vs], vb0, o0b, 0, 0, 0);
      o1a = __builtin_amdgcn_mfma_f32_32x32x16_bf16(paA[vs], vb1, o1a, 0, 0, 0);
      o1b = __builtin_amdgcn_mfma_f32_32x32x16_bf16(paB[vs], vb1, o1b, 0, 0, 0);
    }
    __builtin_amdgcn_s_setprio(0);
    __syncthreads();
  }

  lA += __shfl_xor(lA, 32);
  lB += __shfl_xor(lB, 32);

  // ---- epilogue: unnormalized bf16 partials ----
  short* opA = opart + ((size_t)half * BATCH * NHEADS + bh) * SEQ * 64;
#pragma unroll
  for (int r = 0; r < 16; ++r) {
    const int q = (r & 3) + 8 * (r >> 2) + 4 * hi;
    short* pa_ = opA + (size_t)(q0 + q) * 64;
    pa_[l31] = f2bf(o0a[r]);
    pa_[32 + l31] = f2bf(o1a[r]);
    short* pb_ = opA + (size_t)(q0 + 32 + q) * 64;
    pb_[l31] = f2bf(o0b[r]);
    pb_[32 + l31] = f2bf(o1b[r]);
  }
  if (lane < 32) {
    float* lp = lpart + (size_t)half * BATCH * NHEADS * SEQ + (size_t)bh * SEQ + q0;
    lp[l31] = lA;
    lp[32 + l31] = lB;
  }
}

// ---------------- combine: ctx = (O0+O1)/(l0+l1), bf16 in/out, 8 elems/thread ----
__global__ __launch_bounds__(256) void attn_combine(const short* __restrict__ op,
                                                    const float* __restrict__ lp,
                                                    short* __restrict__ ctx) {
  const size_t HS = (size_t)BATCH * NHEADS * SEQ * 64;  // elems per half
  const int i8 = blockIdx.x * 256 + threadIdx.x;        // 8-elem units
  const size_t base = (size_t)i8 * 8;
  short8 a = *(const short8*)(op + base);
  short8 c = *(const short8*)(op + HS + base);
  const int row = (int)(base >> 6);                     // bh*SEQ + q
  const float inv = frcp(lp[row] + lp[BATCH * NHEADS * SEQ + row]);
  const int bh = row >> 11, q = row & 2047;
  const int b = bh / NHEADS, h = bh - b * NHEADS;
  const int dk = (int)(base & 63);
  short8 o;
#pragma unroll
  for (int j = 0; j < 8; ++j) o[j] = f2bf((bf2f(a[j]) + bf2f(c[j])) * inv);
  *(short8*)(ctx + ((size_t)b * SEQ + q) * D_MODEL + h * 64 + dk) = o;
}

// ---------------- LayerNorm: one wave per row, bf16 in, bf16/f32 out ----------------
template <int OUT_F32>
__global__ __launch_bounds__(256) void ln_w(const short* __restrict__ y,
                                            const float* __restrict__ gw,
                                            const float* __restrict__ bw,
                                            float* __restrict__ of,
                                            short* __restrict__ ob) {
  const int lane = threadIdx.x & 63, w = threadIdx.x >> 6;
  const int row = blockIdx.x * 4 + w;
  const short* yr = y + (size_t)row * D_MODEL;
  short8 v8 = *(const short8*)(yr + lane * 8);
  ushort4v v4 = *(const ushort4v*)(yr + 512 + lane * 4);
  float f[12];
#pragma unroll
  for (int j = 0; j < 8; ++j) f[j] = bf2f(v8[j]);
#pragma unroll
  for (int j = 0; j < 4; ++j) f[8 + j] = bf2f((short)v4[j]);
  float s = 0.f, q = 0.f;
#pragma unroll
  for (int j = 0; j < 12; ++j) { s += f[j]; q += f[j] * f[j]; }
#pragma unroll
  for (int mm = 1; mm < 64; mm <<= 1) {
    s += __shfl_xor(s, mm);
    q += __shfl_xor(q, mm);
  }
  const float mu = s * (1.f / D_MODEL);
  const float rs = rsqrtf(q * (1.f / D_MODEL) - mu * mu + 1e-5f);
  float4v g0 = *(const float4v*)(gw + lane * 8);
  float4v g1 = *(const float4v*)(gw + lane * 8 + 4);
  float4v g2 = *(const float4v*)(gw + 512 + lane * 4);
  float4v b0 = *(const float4v*)(bw + lane * 8);
  float4v b1 = *(const float4v*)(bw + lane * 8 + 4);
  float4v b2 = *(const float4v*)(bw + 512 + lane * 4);
  float o[12];
#pragma unroll
  for (int j = 0; j < 4; ++j) o[j] = (f[j] - mu) * rs * g0[j] + b0[j];
#pragma unroll
  for (int j = 0; j < 4; ++j) o[4 + j] = (f[4 + j] - mu) * rs * g1[j] + b1[j];
#pragma unroll
  for (int j = 0; j < 4; ++j) o[8 + j] = (f[8 + j] - mu) * rs * g2[j] + b2[j];
  if constexpr (OUT_F32) {
    float* orow = of + (size_t)row * D_MODEL;
    float4v t0, t1, t2;
#pragma unroll
    for (int j = 0; j < 4; ++j) { t0[j] = o[j]; t1[j] = o[4 + j]; t2[j] = o[8 + j]; }
    *(float4v*)(orow + lane * 8) = t0;
    *(float4v*)(orow + lane * 8 + 4) = t1;
    *(float4v*)(orow + 512 + lane * 4) = t2;
  } else {
    short* orow = ob + (size_t)row * D_MODEL;
    ushort4v t0, t1, t2;
#pragma unroll
    for (int j = 0; j < 4; ++j) {
      t0[j] = (unsigned short)f2bf(o[j]);
      t1[j] = (unsigned short)f2bf(o[4 + j]);
      t2[j] = (unsigned short)f2bf(o[8 + j]);
    }
    *(ushort4v*)(orow + lane * 8) = t0;
    *(ushort4v*)(orow + lane * 8 + 4) = t1;
    *(ushort4v*)(orow + 512 + lane * 4) = t2;
  }
}

// ---------------- launch ----------------
extern "C" void kernel_launch(void* const* d_in, const int* in_sizes, int n_in,
                              void* d_out, int out_size, void* d_ws, size_t ws_size,
                              hipStream_t stream) {
  const float* emb = (const float*)d_in[0];
  const int* mask = (const int*)d_in[1];
  const float* Wq = (const float*)d_in[2];
  const float* bq = (const float*)d_in[3];
  const float* Wk = (const float*)d_in[4];
  const float* bk = (const float*)d_in[5];
  const float* Wv = (const float*)d_in[6];
  const float* bv = (const float*)d_in[7];
  const float* Wo = (const float*)d_in[8];
  const float* bo = (const float*)d_in[9];
  const float* W1 = (const float*)d_in[10];
  const float* b1 = (const float*)d_in[11];
  const float* W2 = (const float*)d_in[12];
  const float* b2 = (const float*)d_in[13];
  const float* lng = (const float*)d_in[14];
  const float* lnb = (const float*)d_in[15];

  char* ws = (char*)d_ws;
  size_t off = 0;
  auto alloc = [&](size_t bytes) -> char* {
    char* p = ws + off;
    off = (off + bytes + 255) & ~(size_t)255;
    return p;
  };
  const size_t DD = (size_t)D_MODEL * D_MODEL;
  const size_t DF = (size_t)D_MODEL * FF_DIM;
  const size_t TD = (size_t)NTOK * D_MODEL;
  const size_t TF = (size_t)NTOK * FF_DIM;

  short* wqkvt = (short*)alloc(3 * DD * 2);
  short* wot = (short*)alloc(DD * 2);
  short* w1t = (short*)alloc(DF * 2);
  short* w2t = (short*)alloc(DF * 2);
  float* bqkv = (float*)alloc(2304 * 4);
  short* x0 = (short*)alloc(TD * 2);     // emb bf16; reused as ctx after QKV
  short* qkv = (short*)alloc(3 * TD * 2);
  short* aresb = (short*)alloc(TD * 2);
  short* xbf = (short*)alloc(TD * 2);
  short* hbf = (short*)alloc(TF * 2);    // FF hidden; ALSO aliased as opart before FF
  short* ffresb = (short*)alloc(TD * 2);
  float* lpart = (float*)alloc(2 * (size_t)BATCH * NHEADS * SEQ * 4);
  short* qb = qkv;
  short* kb = qkv + TD;
  short* vtb = qkv + 2 * TD;
  short* ctx = x0;
  short* opart = hbf;  // 2*BH*S*64*2B = 25.2MB <= TF*2 bytes; dead before FF1

  prep<<<dim3(1729 + (int)(TD / 1024)), 256, 0, stream>>>(
      Wq, Wk, Wv, Wo, W1, W2, bq, bk, bv, emb, wqkvt, wot, w1t, w2t, bqkv, x0);
  gemm_bt<EPI_QKV><<<dim3(18, 64), 256, 0, stream>>>(
      x0, wqkvt, bqkv, nullptr, nullptr, qkv, NTOK, 3 * D_MODEL, D_MODEL);
  attn_fa6<<<dim3(768), 256, 0, stream>>>(qb, kb, vtb, mask, opart, lpart);
  attn_combine<<<dim3((int)((size_t)BATCH * NHEADS * SEQ * 64 / 8 / 256)), 256, 0, stream>>>(
      opart, lpart, ctx);
  gemm_bt<EPI_WO><<<dim3(6, 64), 256, 0, stream>>>(
      ctx, wot, bo, emb, nullptr, aresb, NTOK, D_MODEL, D_MODEL);
  ln_w<0><<<dim3(NTOK / 4), 256, 0, stream>>>(aresb, lng, lnb, nullptr, xbf);
  gemm_bt<EPI_RELU><<<dim3(24, 64), 256, 0, stream>>>(
      xbf, w1t, b1, nullptr, nullptr, hbf, NTOK, FF_DIM, D_MODEL);
  gemm_bt<EPI_FF><<<dim3(6, 64), 256, 0, stream>>>(
      hbf, w2t, b2, nullptr, xbf, ffresb, NTOK, D_MODEL, FF_DIM);
  ln_w<1><<<dim3(NTOK / 4), 256, 0, stream>>>(ffresb, lng, lnb, (float*)d_out, nullptr);
}